// Round 5
// baseline (1305.838 us; speedup 1.0000x reference)
//
#include <hip/hip_runtime.h>
#include <hip/hip_bf16.h>
#include <math.h>

#define NL 4
#define DM 1024
#define DI 2048
#define DS 16
#define DR 64
#define DC 4
#define B_ 8
#define L_ 224
#define DLOC 672
#define NC 10
#define EPS 1e-5f

#define ROWS (B_ * L_)  // 1792

typedef unsigned short u16;
typedef __attribute__((ext_vector_type(8))) short bf16x8;
typedef __attribute__((ext_vector_type(4))) float f32x4;
typedef __attribute__((address_space(1))) const void gvoid_t;
typedef __attribute__((address_space(3))) void lvoid_t;

__device__ __forceinline__ u16 f2bf(float f) {
  union { float f; unsigned int u; } v;
  v.f = f;
  unsigned int u = v.u;
  return (u16)((u + 0x7fffu + ((u >> 16) & 1u)) >> 16);  // RNE
}

// ---------------------------------------------------------------------------
// bf16 MFMA GEMM (m97 structure): C[M,N](+)=A[M,K]_bf16 @ Bt[N,K]_bf16^T.
// 128x128 tile, 4 waves x (4x4 of 16x16x32). TSTORE=1 stores C^T (ldc = M-dim
// leading dim of the transposed output); fragment r-components are contiguous
// in C^T, so each lane stores one float4 and the wave covers full 64B lines.
// ---------------------------------------------------------------------------
template <int ACC, int BIAS, int TSTORE>
__global__ __launch_bounds__(256) void gemm_bt_mfma(
    const u16* __restrict__ A, const u16* __restrict__ Bt,
    const float* __restrict__ bias, float* __restrict__ C, int K, int lda,
    int ldb, int ldc) {
  __shared__ __align__(16) u16 As[128 * 32];
  __shared__ __align__(16) u16 Bs[128 * 32];
  const int tid = threadIdx.x;
  const int lane = tid & 63;
  const int wv = tid >> 6;
  const int n0 = blockIdx.x * 128;
  const int m0 = blockIdx.y * 128;
  const int wm0 = (wv & 1) * 64;
  const int wn0 = (wv >> 1) * 64;
  const int quad = lane >> 4;
  const int l16 = lane & 15;

  const int srow = wv * 32 + (lane >> 2);
  const int scol = (lane & 3) * 8;
  const u16* ga0 = A + (size_t)(m0 + srow) * lda + scol;
  const u16* ga1 = ga0 + (size_t)16 * lda;
  const u16* gb0 = Bt + (size_t)(n0 + srow) * ldb + scol;
  const u16* gb1 = gb0 + (size_t)16 * ldb;
  u16* la0 = &As[(wv * 32) * 32];
  u16* la1 = &As[(wv * 32 + 16) * 32];
  u16* lb0 = &Bs[(wv * 32) * 32];
  u16* lb1 = &Bs[(wv * 32 + 16) * 32];

  f32x4 acc[4][4] = {};

  for (int k0 = 0; k0 < K; k0 += 32) {
    __syncthreads();
    __builtin_amdgcn_global_load_lds((gvoid_t*)ga0, (lvoid_t*)la0, 16, 0, 0);
    __builtin_amdgcn_global_load_lds((gvoid_t*)ga1, (lvoid_t*)la1, 16, 0, 0);
    __builtin_amdgcn_global_load_lds((gvoid_t*)gb0, (lvoid_t*)lb0, 16, 0, 0);
    __builtin_amdgcn_global_load_lds((gvoid_t*)gb1, (lvoid_t*)lb1, 16, 0, 0);
    __syncthreads();
    bf16x8 af[4], bfr[4];
#pragma unroll
    for (int i = 0; i < 4; i++)
      af[i] = *(const bf16x8*)&As[(wm0 + i * 16 + l16) * 32 + quad * 8];
#pragma unroll
    for (int j = 0; j < 4; j++)
      bfr[j] = *(const bf16x8*)&Bs[(wn0 + j * 16 + l16) * 32 + quad * 8];
#pragma unroll
    for (int i = 0; i < 4; i++)
#pragma unroll
      for (int j = 0; j < 4; j++)
        acc[i][j] = __builtin_amdgcn_mfma_f32_16x16x32_bf16(af[i], bfr[j],
                                                            acc[i][j], 0, 0, 0);
    ga0 += 32; ga1 += 32; gb0 += 32; gb1 += 32;
  }

#pragma unroll
  for (int i = 0; i < 4; i++) {
#pragma unroll
    for (int j = 0; j < 4; j++) {
      const int col = n0 + wn0 + j * 16 + l16;
      const int rowb = m0 + wm0 + i * 16 + quad * 4;
      if (TSTORE) {
        *(f32x4*)(C + (size_t)col * ldc + rowb) = acc[i][j];
      } else {
        float bv = 0.f;
        if (BIAS) bv = bias[col];
#pragma unroll
        for (int r = 0; r < 4; r++) {
          float v = acc[i][j][r] + bv;
          float* p = C + (size_t)(rowb + r) * ldc + col;
          if (ACC) v += *p;
          *p = v;
        }
      }
    }
  }
}

// ---------------------------------------------------------------------------
// fp32 tiled GEMM. ACC: 0=store, 1=+=, 2=atomicAdd. ACT 1 = softplus.
// BROW: 0 no bias, 1 bias[n], 2 bias[m]. SPLITK: z-dim K chunks of 256.
// Stores guarded on m<M and n<N (A-tile reads may run past M rows; callers
// guarantee the overread stays inside the workspace).
// ---------------------------------------------------------------------------
template <int ACC, int ACT, int SPLITK, int BROW>
__global__ __launch_bounds__(256) void gemm_kernel(
    const float* __restrict__ A, const float* __restrict__ Bm,
    const float* __restrict__ bias, float* __restrict__ C, int M, int N, int K,
    int lda, int ldb, int ldc) {
  if (SPLITK) {
    A += (size_t)blockIdx.z * 256;
    Bm += (size_t)blockIdx.z * 256 * ldb;
  }
  __shared__ float As[16][64];
  __shared__ float Bs[16][64];
  const int tid = threadIdx.x;
  const int tx = tid & 15;
  const int ty = tid >> 4;
  const int n0 = blockIdx.x * 64;
  const int m0 = blockIdx.y * 64;
  const int am = tid & 63;
  const int ak = (tid >> 6) * 4;
  const int bk = tid >> 4;
  const int bn = (tid & 15) * 4;

  float acc[4][4];
#pragma unroll
  for (int i = 0; i < 4; i++)
#pragma unroll
    for (int j = 0; j < 4; j++) acc[i][j] = 0.f;

  for (int k0 = 0; k0 < K; k0 += 16) {
    float4 av = *(const float4*)(A + (size_t)(m0 + am) * lda + k0 + ak);
    float4 bv;
    {
      int n = n0 + bn;
      const float* bp = Bm + (size_t)(k0 + bk) * ldb + n;
      if (n + 3 < N) {
        bv = *(const float4*)bp;
      } else {
        bv.x = (n + 0 < N) ? bp[0] : 0.f;
        bv.y = (n + 1 < N) ? bp[1] : 0.f;
        bv.z = (n + 2 < N) ? bp[2] : 0.f;
        bv.w = (n + 3 < N) ? bp[3] : 0.f;
      }
    }
    __syncthreads();
    As[ak + 0][am] = av.x;
    As[ak + 1][am] = av.y;
    As[ak + 2][am] = av.z;
    As[ak + 3][am] = av.w;
    *(float4*)(&Bs[bk][bn]) = bv;
    __syncthreads();
#pragma unroll
    for (int kk = 0; kk < 16; kk++) {
      float4 a4 = *(const float4*)(&As[kk][ty * 4]);
      float4 b4 = *(const float4*)(&Bs[kk][tx * 4]);
      float ar[4] = {a4.x, a4.y, a4.z, a4.w};
      float br[4] = {b4.x, b4.y, b4.z, b4.w};
#pragma unroll
      for (int i = 0; i < 4; i++)
#pragma unroll
        for (int j = 0; j < 4; j++) acc[i][j] = fmaf(ar[i], br[j], acc[i][j]);
    }
  }

#pragma unroll
  for (int i = 0; i < 4; i++) {
    int m = m0 + ty * 4 + i;
#pragma unroll
    for (int j = 0; j < 4; j++) {
      int n = n0 + tx * 4 + j;
      if (n < N && m < M) {
        float v = acc[i][j];
        if (BROW == 1) v += bias[n];
        if (BROW == 2) v += bias[m];
        if (ACT == 1) v = (v > 20.f) ? v : log1pf(expf(v));  // softplus
        float* p = C + (size_t)m * ldc + n;
        if (ACC == 2) {
          atomicAdd(p, v);
        } else {
          if (ACC == 1) v += *p;
          *p = v;
        }
      }
    }
  }
}

// ---------------------------------------------------------------------------
// fp32 [K,N] -> bf16 [N,K] transpose+convert, 32x32 LDS tiles
// ---------------------------------------------------------------------------
__global__ __launch_bounds__(256) void transpose_cvt_kernel(
    const float* __restrict__ src, u16* __restrict__ dst, int K, int N) {
  __shared__ float t[32][33];
  const int n0 = blockIdx.x * 32;
  const int k0 = blockIdx.y * 32;
  const int c = threadIdx.x & 31;
  const int r = threadIdx.x >> 5;  // 0..7
#pragma unroll
  for (int rr = 0; rr < 4; rr++)
    t[r + rr * 8][c] = src[(size_t)(k0 + r + rr * 8) * N + n0 + c];
  __syncthreads();
#pragma unroll
  for (int rr = 0; rr < 4; rr++)
    dst[(size_t)(n0 + r + rr * 8) * K + k0 + c] = f2bf(t[c][r + rr * 8]);
}

// fp32 [K,N] -> fp32 [N,K] transpose
__global__ __launch_bounds__(256) void transpose_f32_kernel(
    const float* __restrict__ src, float* __restrict__ dst, int K, int N) {
  __shared__ float t[32][33];
  const int n0 = blockIdx.x * 32;
  const int k0 = blockIdx.y * 32;
  const int c = threadIdx.x & 31;
  const int r = threadIdx.x >> 5;
#pragma unroll
  for (int rr = 0; rr < 4; rr++)
    t[r + rr * 8][c] = src[(size_t)(k0 + r + rr * 8) * N + n0 + c];
  __syncthreads();
#pragma unroll
  for (int rr = 0; rr < 4; rr++)
    dst[(size_t)(n0 + r + rr * 8) * K + k0 + c] = t[c][r + rr * 8];
}

// flat fp32 -> bf16, 4 elems/thread
__global__ __launch_bounds__(256) void cvt_kernel(const float* __restrict__ src,
                                                  u16* __restrict__ dst) {
  const int i = blockIdx.x * 256 + threadIdx.x;
  const float4 v = ((const float4*)src)[i];
  ushort4 o;
  o.x = f2bf(v.x);
  o.y = f2bf(v.y);
  o.z = f2bf(v.z);
  o.w = f2bf(v.w);
  ((ushort4*)dst)[i] = o;
}

// ---------------------------------------------------------------------------
// RMSNorm -> bf16 out
// ---------------------------------------------------------------------------
__global__ __launch_bounds__(256) void rmsnorm_kernel(
    const float* __restrict__ h, const float* __restrict__ w,
    u16* __restrict__ out) {
  const int row = blockIdx.x;
  const int tid = threadIdx.x;
  const float4 v = *(const float4*)(h + (size_t)row * DM + tid * 4);
  float ss = v.x * v.x + v.y * v.y + v.z * v.z + v.w * v.w;
#pragma unroll
  for (int off = 32; off > 0; off >>= 1) ss += __shfl_xor(ss, off);
  __shared__ float red[4];
  if ((tid & 63) == 0) red[tid >> 6] = ss;
  __syncthreads();
  float tot = red[0] + red[1] + red[2] + red[3];
  const float inv = rsqrtf(tot / (float)DM + EPS);
  const float4 wv = *(const float4*)(w + tid * 4);
  ushort4 o;
  o.x = f2bf(v.x * inv * wv.x);
  o.y = f2bf(v.y * inv * wv.y);
  o.z = f2bf(v.z * inv * wv.z);
  o.w = f2bf(v.w * inv * wv.w);
  *(ushort4*)(out + (size_t)row * DM + tid * 4) = o;
}

// ---------------------------------------------------------------------------
// Causal depthwise conv + bias + silu, channel-major:
// xpT[d][row] (= xzT rows 0..DI-1) -> uT[d][row]. One thread per (d, 4 rows).
// t0 = row%L_ is a multiple of 4, so the 3-tap history is in-batch iff t0>0.
// ---------------------------------------------------------------------------
__global__ __launch_bounds__(256) void conv_silu_t_kernel(
    const float* __restrict__ xpT, const float* __restrict__ wc,
    const float* __restrict__ bc, float* __restrict__ uT) {
  const int idx = blockIdx.x * 256 + threadIdx.x;  // over DI * ROWS/4
  const int d = idx / (ROWS / 4);
  const int r4 = (idx - d * (ROWS / 4)) * 4;
  const int t0 = r4 % L_;
  const float* row = xpT + (size_t)d * ROWS + r4;
  const float4 v = *(const float4*)row;
  float p0 = 0.f, p1 = 0.f, p2 = 0.f;
  if (t0 > 0) { p0 = row[-3]; p1 = row[-2]; p2 = row[-1]; }
  const float w0 = wc[d * 4 + 0], w1 = wc[d * 4 + 1], w2 = wc[d * 4 + 2],
              w3 = wc[d * 4 + 3];
  const float bb = bc[d];
  float4 o;
  float s;
  s = bb + p0 * w0 + p1 * w1 + p2 * w2 + v.x * w3; o.x = s / (1.f + expf(-s));
  s = bb + p1 * w0 + p2 * w1 + v.x * w2 + v.y * w3; o.y = s / (1.f + expf(-s));
  s = bb + p2 * w0 + v.x * w1 + v.y * w2 + v.z * w3; o.z = s / (1.f + expf(-s));
  s = bb + v.x * w0 + v.y * w1 + v.z * w2 + v.w * w3; o.w = s / (1.f + expf(-s));
  *(float4*)(uT + (size_t)d * ROWS + r4) = o;
}

// ---------------------------------------------------------------------------
// Selective scan v4: channel-major streams, no LDS.
// 4096 one-wave blocks (4 ch/wave, 1 state/lane). lane=(c<<4)|s.
// dt/u/z float4 loads broadcast across the 16 s-lanes of a channel
// (coalesces to one request); B/C rows are L2-resident (688 KB, 512x reuse).
// Register double-buffer one 4-step sub-chunk ahead.
// ---------------------------------------------------------------------------
__global__ __launch_bounds__(64) void scan_kernel(
    const float* __restrict__ dtT, const float* __restrict__ uT,
    const float* __restrict__ xdblT, const float* __restrict__ zT,
    const float* __restrict__ A_log, const float* __restrict__ Dp,
    u16* __restrict__ y) {
  const int lane = threadIdx.x;
  const int b = blockIdx.x >> 9;           // 512 blocks per batch
  const int d0 = (blockIdx.x & 511) << 2;  // 4 channels per wave
  const int c = lane >> 4;
  const int s = lane & 15;
  const int d = d0 + c;

  const float A2 = -expf(A_log[(size_t)d * DS + s]) * 1.44269504f;
  const float Dpd = Dp[d];

  const float* dtp = dtT + (size_t)d * ROWS + b * L_;
  const float* up = uT + (size_t)d * ROWS + b * L_;
  const float* zp = zT + (size_t)d * ROWS + b * L_;
  const float* Bp = xdblT + (size_t)(DR + s) * ROWS + b * L_;
  const float* Cp = xdblT + (size_t)(DR + DS + s) * ROWS + b * L_;
  u16* yp = y + (size_t)(b * L_) * DI + d;

  float hs = 0.f;
  float4 dv = *(const float4*)dtp;
  float4 uv = *(const float4*)up;
  float4 zv = *(const float4*)zp;
  float4 Bv = *(const float4*)Bp;
  float4 Cv = *(const float4*)Cp;

  for (int t0 = 0; t0 < L_; t0 += 4) {
    float4 dn, un, zn, Bn, Cn;
    if (t0 + 4 < L_) {
      dn = *(const float4*)(dtp + t0 + 4);
      un = *(const float4*)(up + t0 + 4);
      zn = *(const float4*)(zp + t0 + 4);
      Bn = *(const float4*)(Bp + t0 + 4);
      Cn = *(const float4*)(Cp + t0 + 4);
    }
    const float* dvv = (const float*)&dv;
    const float* uvv = (const float*)&uv;
    const float* zvv = (const float*)&zv;
    const float* Bvv = (const float*)&Bv;
    const float* Cvv = (const float*)&Cv;
#pragma unroll
    for (int k = 0; k < 4; k++) {
      const float dtv = dvv[k];
      const float uu = uvv[k];
      const float e = exp2f(dtv * A2);
      hs = fmaf(hs, e, dtv * uu * Bvv[k]);
      float pr = hs * Cvv[k];
      pr += __shfl_xor(pr, 1);
      pr += __shfl_xor(pr, 2);
      pr += __shfl_xor(pr, 4);
      pr += __shfl_xor(pr, 8);
      if (s == 0) {
        const float zz = zvv[k];
        float yv = pr + Dpd * uu;
        yv *= zz / (1.f + expf(-zz));
        yp[(size_t)(t0 + k) * DI] = f2bf(yv);
      }
    }
    dv = dn; uv = un; zv = zn; Bv = Bn; Cv = Cn;
  }
}

// ---------------------------------------------------------------------------
// Final: rmsnorm(h[b, L-1, :]) @ w_fc + b_fc
// ---------------------------------------------------------------------------
__global__ __launch_bounds__(256) void final_kernel(
    const float* __restrict__ h, const float* __restrict__ fnw,
    const float* __restrict__ w_fc, const float* __restrict__ b_fc,
    float* __restrict__ out) {
  const int b = blockIdx.x;
  const int tid = threadIdx.x;
  const size_t row = ((size_t)b * L_ + (L_ - 1)) * DM;
  const float4 v = *(const float4*)(h + row + tid * 4);
  float ss = v.x * v.x + v.y * v.y + v.z * v.z + v.w * v.w;
#pragma unroll
  for (int off = 32; off > 0; off >>= 1) ss += __shfl_xor(ss, off);
  __shared__ float red[4];
  if ((tid & 63) == 0) red[tid >> 6] = ss;
  __syncthreads();
  float tot = red[0] + red[1] + red[2] + red[3];
  const float inv = rsqrtf(tot / (float)DM + EPS);
  const float4 wv = *(const float4*)(fnw + tid * 4);
  float hn[4] = {v.x * inv * wv.x, v.y * inv * wv.y, v.z * inv * wv.z,
                 v.w * inv * wv.w};
  float partial[NC];
#pragma unroll
  for (int j = 0; j < NC; j++) partial[j] = 0.f;
#pragma unroll
  for (int e = 0; e < 4; e++) {
    const int dd = tid * 4 + e;
#pragma unroll
    for (int j = 0; j < NC; j++)
      partial[j] = fmaf(hn[e], w_fc[dd * NC + j], partial[j]);
  }
  __shared__ float red2[256][NC];
  for (int j = 0; j < NC; j++) red2[tid][j] = partial[j];
  __syncthreads();
  for (int stride = 128; stride > 0; stride >>= 1) {
    if (tid < stride)
      for (int j = 0; j < NC; j++) red2[tid][j] += red2[tid + stride][j];
    __syncthreads();
  }
  if (tid < NC) out[b * NC + tid] = red2[0][tid] + b_fc[tid];
}

// ---------------------------------------------------------------------------
extern "C" void kernel_launch(void* const* d_in, const int* in_sizes, int n_in,
                              void* d_out, int out_size, void* d_ws,
                              size_t ws_size, hipStream_t stream) {
  const float* x = (const float*)d_in[0];
  const float* w_proj = (const float*)d_in[1];
  const float* b_proj = (const float*)d_in[2];
  const float* norm_w = (const float*)d_in[3];
  const float* w_in = (const float*)d_in[4];
  const float* w_conv = (const float*)d_in[5];
  const float* b_conv = (const float*)d_in[6];
  const float* w_x = (const float*)d_in[7];
  const float* w_dt = (const float*)d_in[8];
  const float* b_dt = (const float*)d_in[9];
  const float* A_log = (const float*)d_in[10];
  const float* Dp = (const float*)d_in[11];
  const float* w_out = (const float*)d_in[12];
  const float* fnw = (const float*)d_in[13];
  const float* w_fc = (const float*)d_in[14];
  const float* b_fc = (const float*)d_in[15];
  float* out = (float*)d_out;

  // Workspace layout (float units)
  float* ws = (float*)d_ws;
  float* h = ws;                          // 1,835,008
  float* xzT = h + 1835008;               // 7,340,032  [4096][1792]
  float* uT = xzT + 7340032;              // 3,670,016  [2048][1792]
  float* xdblT = uT + 3670016;            //   172,032  [96][1792]
  float* dtT = xdblT + 172032;            // 3,670,016  [2048][1792]
  float* nxt = dtT + 3670016;
  u16* y16 = (u16*)nxt;                   // 1,835,008 f  (bf16 [row][DI])
  u16* xn16 = y16;                        // alias (disjoint liveness)
  u16* x16 = (u16*)(nxt + 1835008);       //   602,112 f
  u16* wprojT = (u16*)(nxt + 2437120);    //   344,064 f
  u16* winT = (u16*)(nxt + 2781184);      // 2,097,152 f
  u16* woutT = (u16*)(nxt + 4878336);     // 1,048,576 f
  float* w_xT = nxt + 5926912;            //   196,608  [96][2048]
  float* w_dtT = w_xT + 196608;           //   131,072  [2048][64]
  // (w_dtT directly after w_xT: the M-guarded w_x GEMM overreads A rows
  //  96..127, which land harmlessly in w_dtT.)

  const dim3 blk(256);

  cvt_kernel<<<ROWS * DLOC / 1024, blk, 0, stream>>>(x, x16);
  transpose_cvt_kernel<<<dim3(DM / 32, DLOC / 32), blk, 0, stream>>>(
      w_proj, wprojT, DLOC, DM);

  // h = x @ w_proj + b_proj (bf16 MFMA, row-major out)
  gemm_bt_mfma<0, 1, 0><<<dim3(DM / 128, ROWS / 128), blk, 0, stream>>>(
      x16, wprojT, b_proj, h, DLOC, DLOC, DLOC, DM);

  for (int l = 0; l < NL; l++) {
    transpose_cvt_kernel<<<dim3(2 * DI / 32, DM / 32), blk, 0, stream>>>(
        w_in + (size_t)l * DM * 2 * DI, winT, DM, 2 * DI);
    transpose_cvt_kernel<<<dim3(DM / 32, DI / 32), blk, 0, stream>>>(
        w_out + (size_t)l * DI * DM, woutT, DI, DM);
    // w_xT[96][2048] = w_x[l]^T ; w_dtT[2048][64] = w_dt[l]^T
    transpose_f32_kernel<<<dim3(96 / 32, DI / 32), blk, 0, stream>>>(
        w_x + (size_t)l * DI * 96, w_xT, DI, 96);
    transpose_f32_kernel<<<dim3(DI / 32, DR / 32), blk, 0, stream>>>(
        w_dt + (size_t)l * DR * DI, w_dtT, DR, DI);

    // xn = rmsnorm(h) -> bf16
    rmsnorm_kernel<<<ROWS, blk, 0, stream>>>(h, norm_w + (size_t)l * DM, xn16);
    // xzT = (xn @ w_in[l])^T  (MFMA, transposed store)
    gemm_bt_mfma<0, 0, 1><<<dim3(2 * DI / 128, ROWS / 128), blk, 0, stream>>>(
        xn16, winT, nullptr, xzT, DM, DM, DM, ROWS);
    // uT = silu(conv(xpT) + b_conv), channel-major
    conv_silu_t_kernel<<<DI * (ROWS / 4) / 256, blk, 0, stream>>>(
        xzT, w_conv + (size_t)l * DI * DC, b_conv + (size_t)l * DI, uT);
    // xdblT[96][1792] = w_xT @ uT   (fp32 split-K x8 + atomics, M-guarded)
    hipMemsetAsync(xdblT, 0, (size_t)96 * ROWS * sizeof(float), stream);
    gemm_kernel<2, 0, 1, 0><<<dim3(ROWS / 64, 2, 8), blk, 0, stream>>>(
        w_xT, uT, nullptr, xdblT, 96, ROWS, 256, DI, ROWS, ROWS);
    // dtT[2048][1792] = softplus(w_dtT @ dtrT + b_dt[m])  (fp32, K=64)
    gemm_kernel<0, 1, 0, 2><<<dim3(ROWS / 64, DI / 64), blk, 0, stream>>>(
        w_dtT, xdblT, b_dt + (size_t)l * DI, dtT, DI, ROWS, DR, DR, ROWS,
        ROWS);
    // y16[row][d] = scan(...)  (4096 one-wave blocks, channel-major streams)
    scan_kernel<<<B_ * (DI / 4), dim3(64), 0, stream>>>(
        dtT, uT, xdblT, xzT + (size_t)DI * ROWS, A_log + (size_t)l * DI * DS,
        Dp + (size_t)l * DI, y16);
    // h += y @ w_out[l]  (MFMA, row-major out)
    gemm_bt_mfma<1, 0, 0><<<dim3(DM / 128, ROWS / 128), blk, 0, stream>>>(
        y16, woutT, nullptr, h, DI, DI, DI, DM);
  }

  final_kernel<<<B_, blk, 0, stream>>>(h, fnw, w_fc, b_fc, out);
}

// Round 6
// 1245.911 us; speedup vs baseline: 1.0481x; 1.0481x over previous
//
#include <hip/hip_runtime.h>
#include <hip/hip_bf16.h>
#include <hip/hip_fp16.h>
#include <math.h>

#define NL 4
#define DM 1024
#define DI 2048
#define DS 16
#define DR 64
#define DC 4
#define B_ 8
#define L_ 224
#define DLOC 672
#define NC 10
#define EPS 1e-5f

#define ROWS (B_ * L_)  // 1792

typedef unsigned short u16;
typedef __attribute__((ext_vector_type(8))) short bf16x8;
typedef __attribute__((ext_vector_type(4))) float f32x4;
typedef __attribute__((address_space(1))) const void gvoid_t;
typedef __attribute__((address_space(3))) void lvoid_t;

__device__ __forceinline__ u16 f2bf(float f) {
  union { float f; unsigned int u; } v;
  v.f = f;
  unsigned int u = v.u;
  return (u16)((u + 0x7fffu + ((u >> 16) & 1u)) >> 16);  // RNE
}

// load 4 consecutive halfs (8B aligned) -> 4 floats
__device__ __forceinline__ void load4h(const __half* p, float* o) {
  uint2 r = *(const uint2*)p;
  __half2 h0 = *(__half2*)&r.x;
  __half2 h1 = *(__half2*)&r.y;
  float2 f0 = __half22float2(h0);
  float2 f1 = __half22float2(h1);
  o[0] = f0.x; o[1] = f0.y; o[2] = f1.x; o[3] = f1.y;
}

// ---------------------------------------------------------------------------
// bf16 MFMA GEMM: C[M,N](+)=A[M,K]_bf16 @ Bt[N,K]_bf16^T. 128x128 tile.
// TSTORE=1: store C^T as fp16 (ldc = leading dim of transposed output).
// ---------------------------------------------------------------------------
template <int ACC, int BIAS, int TSTORE>
__global__ __launch_bounds__(256) void gemm_bt_mfma(
    const u16* __restrict__ A, const u16* __restrict__ Bt,
    const float* __restrict__ bias, float* __restrict__ C, int K, int lda,
    int ldb, int ldc) {
  __shared__ __align__(16) u16 As[128 * 32];
  __shared__ __align__(16) u16 Bs[128 * 32];
  const int tid = threadIdx.x;
  const int lane = tid & 63;
  const int wv = tid >> 6;
  const int n0 = blockIdx.x * 128;
  const int m0 = blockIdx.y * 128;
  const int wm0 = (wv & 1) * 64;
  const int wn0 = (wv >> 1) * 64;
  const int quad = lane >> 4;
  const int l16 = lane & 15;

  const int srow = wv * 32 + (lane >> 2);
  const int scol = (lane & 3) * 8;
  const u16* ga0 = A + (size_t)(m0 + srow) * lda + scol;
  const u16* ga1 = ga0 + (size_t)16 * lda;
  const u16* gb0 = Bt + (size_t)(n0 + srow) * ldb + scol;
  const u16* gb1 = gb0 + (size_t)16 * ldb;
  u16* la0 = &As[(wv * 32) * 32];
  u16* la1 = &As[(wv * 32 + 16) * 32];
  u16* lb0 = &Bs[(wv * 32) * 32];
  u16* lb1 = &Bs[(wv * 32 + 16) * 32];

  f32x4 acc[4][4] = {};

  for (int k0 = 0; k0 < K; k0 += 32) {
    __syncthreads();
    __builtin_amdgcn_global_load_lds((gvoid_t*)ga0, (lvoid_t*)la0, 16, 0, 0);
    __builtin_amdgcn_global_load_lds((gvoid_t*)ga1, (lvoid_t*)la1, 16, 0, 0);
    __builtin_amdgcn_global_load_lds((gvoid_t*)gb0, (lvoid_t*)lb0, 16, 0, 0);
    __builtin_amdgcn_global_load_lds((gvoid_t*)gb1, (lvoid_t*)lb1, 16, 0, 0);
    __syncthreads();
    bf16x8 af[4], bfr[4];
#pragma unroll
    for (int i = 0; i < 4; i++)
      af[i] = *(const bf16x8*)&As[(wm0 + i * 16 + l16) * 32 + quad * 8];
#pragma unroll
    for (int j = 0; j < 4; j++)
      bfr[j] = *(const bf16x8*)&Bs[(wn0 + j * 16 + l16) * 32 + quad * 8];
#pragma unroll
    for (int i = 0; i < 4; i++)
#pragma unroll
      for (int j = 0; j < 4; j++)
        acc[i][j] = __builtin_amdgcn_mfma_f32_16x16x32_bf16(af[i], bfr[j],
                                                            acc[i][j], 0, 0, 0);
    ga0 += 32; ga1 += 32; gb0 += 32; gb1 += 32;
  }

#pragma unroll
  for (int i = 0; i < 4; i++) {
#pragma unroll
    for (int j = 0; j < 4; j++) {
      const int col = n0 + wn0 + j * 16 + l16;
      const int rowb = m0 + wm0 + i * 16 + quad * 4;
      if (TSTORE) {
        __half* Ch = (__half*)C;
        __half2 p0, p1;
        p0.x = __float2half(acc[i][j][0]); p0.y = __float2half(acc[i][j][1]);
        p1.x = __float2half(acc[i][j][2]); p1.y = __float2half(acc[i][j][3]);
        union { __half2 h[2]; uint2 u; } pk;
        pk.h[0] = p0; pk.h[1] = p1;
        *(uint2*)(Ch + (size_t)col * ldc + rowb) = pk.u;
      } else {
        float bv = 0.f;
        if (BIAS) bv = bias[col];
#pragma unroll
        for (int r = 0; r < 4; r++) {
          float v = acc[i][j][r] + bv;
          float* p = C + (size_t)(rowb + r) * ldc + col;
          if (ACC) v += *p;
          *p = v;
        }
      }
    }
  }
}

// ---------------------------------------------------------------------------
// fp32-accum tiled GEMM, templated operand/output types.
// ACC: 0=store, 2=atomicAdd(float). ACT 1 = softplus. BROW: 0 none, 2 bias[m].
// ---------------------------------------------------------------------------
template <int ACC, int ACT, int SPLITK, int BROW, typename BT, typename OT>
__global__ __launch_bounds__(256) void gemm_kernel(
    const float* __restrict__ A, const BT* __restrict__ Bm,
    const float* __restrict__ bias, OT* __restrict__ C, int M, int N, int K,
    int lda, int ldb, int ldc) {
  if (SPLITK) {
    A += (size_t)blockIdx.z * 256;
    Bm += (size_t)blockIdx.z * 256 * ldb;
  }
  __shared__ float As[16][64];
  __shared__ float Bs[16][64];
  const int tid = threadIdx.x;
  const int tx = tid & 15;
  const int ty = tid >> 4;
  const int n0 = blockIdx.x * 64;
  const int m0 = blockIdx.y * 64;
  const int am = tid & 63;
  const int ak = (tid >> 6) * 4;
  const int bk = tid >> 4;
  const int bn = (tid & 15) * 4;

  float acc[4][4];
#pragma unroll
  for (int i = 0; i < 4; i++)
#pragma unroll
    for (int j = 0; j < 4; j++) acc[i][j] = 0.f;

  for (int k0 = 0; k0 < K; k0 += 16) {
    float4 av = *(const float4*)(A + (size_t)(m0 + am) * lda + k0 + ak);
    float4 bv;
    {
      int n = n0 + bn;
      const BT* bp = Bm + (size_t)(k0 + bk) * ldb + n;
      if (n + 3 < N) {
        if (sizeof(BT) == 2) {
          load4h((const __half*)bp, (float*)&bv);
        } else {
          bv = *(const float4*)(const void*)bp;
        }
      } else {
        bv.x = (n + 0 < N) ? (float)bp[0] : 0.f;
        bv.y = (n + 1 < N) ? (float)bp[1] : 0.f;
        bv.z = (n + 2 < N) ? (float)bp[2] : 0.f;
        bv.w = (n + 3 < N) ? (float)bp[3] : 0.f;
      }
    }
    __syncthreads();
    As[ak + 0][am] = av.x;
    As[ak + 1][am] = av.y;
    As[ak + 2][am] = av.z;
    As[ak + 3][am] = av.w;
    *(float4*)(&Bs[bk][bn]) = bv;
    __syncthreads();
#pragma unroll
    for (int kk = 0; kk < 16; kk++) {
      float4 a4 = *(const float4*)(&As[kk][ty * 4]);
      float4 b4 = *(const float4*)(&Bs[kk][tx * 4]);
      float ar[4] = {a4.x, a4.y, a4.z, a4.w};
      float br[4] = {b4.x, b4.y, b4.z, b4.w};
#pragma unroll
      for (int i = 0; i < 4; i++)
#pragma unroll
        for (int j = 0; j < 4; j++) acc[i][j] = fmaf(ar[i], br[j], acc[i][j]);
    }
  }

#pragma unroll
  for (int i = 0; i < 4; i++) {
    int m = m0 + ty * 4 + i;
#pragma unroll
    for (int j = 0; j < 4; j++) {
      int n = n0 + tx * 4 + j;
      if (n < N && m < M) {
        float v = acc[i][j];
        if (BROW == 2) v += bias[m];
        if (ACT == 1) v = (v > 20.f) ? v : log1pf(expf(v));  // softplus
        OT* p = C + (size_t)m * ldc + n;
        if (ACC == 2) {
          atomicAdd((float*)p, v);
        } else {
          *p = (OT)v;
        }
      }
    }
  }
}

// ---------------------------------------------------------------------------
// fp32 [K,N] -> bf16 [N,K] transpose+convert
// ---------------------------------------------------------------------------
__global__ __launch_bounds__(256) void transpose_cvt_kernel(
    const float* __restrict__ src, u16* __restrict__ dst, int K, int N) {
  __shared__ float t[32][33];
  const int n0 = blockIdx.x * 32;
  const int k0 = blockIdx.y * 32;
  const int c = threadIdx.x & 31;
  const int r = threadIdx.x >> 5;
#pragma unroll
  for (int rr = 0; rr < 4; rr++)
    t[r + rr * 8][c] = src[(size_t)(k0 + r + rr * 8) * N + n0 + c];
  __syncthreads();
#pragma unroll
  for (int rr = 0; rr < 4; rr++)
    dst[(size_t)(n0 + r + rr * 8) * K + k0 + c] = f2bf(t[c][r + rr * 8]);
}

// fp32 [K,N] -> fp32 [N,K]
__global__ __launch_bounds__(256) void transpose_f32_kernel(
    const float* __restrict__ src, float* __restrict__ dst, int K, int N) {
  __shared__ float t[32][33];
  const int n0 = blockIdx.x * 32;
  const int k0 = blockIdx.y * 32;
  const int c = threadIdx.x & 31;
  const int r = threadIdx.x >> 5;
#pragma unroll
  for (int rr = 0; rr < 4; rr++)
    t[r + rr * 8][c] = src[(size_t)(k0 + r + rr * 8) * N + n0 + c];
  __syncthreads();
#pragma unroll
  for (int rr = 0; rr < 4; rr++)
    dst[(size_t)(n0 + r + rr * 8) * K + k0 + c] = t[c][r + rr * 8];
}

// u16 [K,N] -> u16 [N,K]  (yT -> y row-major)
__global__ __launch_bounds__(256) void transpose_u16_kernel(
    const u16* __restrict__ src, u16* __restrict__ dst, int K, int N) {
  __shared__ u16 t[32][33];
  const int n0 = blockIdx.x * 32;
  const int k0 = blockIdx.y * 32;
  const int c = threadIdx.x & 31;
  const int r = threadIdx.x >> 5;
#pragma unroll
  for (int rr = 0; rr < 4; rr++)
    t[r + rr * 8][c] = src[(size_t)(k0 + r + rr * 8) * N + n0 + c];
  __syncthreads();
#pragma unroll
  for (int rr = 0; rr < 4; rr++)
    dst[(size_t)(n0 + r + rr * 8) * K + k0 + c] = t[c][r + rr * 8];
}

// flat fp32 -> bf16
__global__ __launch_bounds__(256) void cvt_kernel(const float* __restrict__ src,
                                                  u16* __restrict__ dst) {
  const int i = blockIdx.x * 256 + threadIdx.x;
  const float4 v = ((const float4*)src)[i];
  ushort4 o;
  o.x = f2bf(v.x);
  o.y = f2bf(v.y);
  o.z = f2bf(v.z);
  o.w = f2bf(v.w);
  ((ushort4*)dst)[i] = o;
}

// ---------------------------------------------------------------------------
// RMSNorm -> bf16
// ---------------------------------------------------------------------------
__global__ __launch_bounds__(256) void rmsnorm_kernel(
    const float* __restrict__ h, const float* __restrict__ w,
    u16* __restrict__ out) {
  const int row = blockIdx.x;
  const int tid = threadIdx.x;
  const float4 v = *(const float4*)(h + (size_t)row * DM + tid * 4);
  float ss = v.x * v.x + v.y * v.y + v.z * v.z + v.w * v.w;
#pragma unroll
  for (int off = 32; off > 0; off >>= 1) ss += __shfl_xor(ss, off);
  __shared__ float red[4];
  if ((tid & 63) == 0) red[tid >> 6] = ss;
  __syncthreads();
  float tot = red[0] + red[1] + red[2] + red[3];
  const float inv = rsqrtf(tot / (float)DM + EPS);
  const float4 wv = *(const float4*)(w + tid * 4);
  ushort4 o;
  o.x = f2bf(v.x * inv * wv.x);
  o.y = f2bf(v.y * inv * wv.y);
  o.z = f2bf(v.z * inv * wv.z);
  o.w = f2bf(v.w * inv * wv.w);
  *(ushort4*)(out + (size_t)row * DM + tid * 4) = o;
}

// ---------------------------------------------------------------------------
// Causal depthwise conv + bias + silu, channel-major fp16 -> fp16
// ---------------------------------------------------------------------------
__global__ __launch_bounds__(256) void conv_silu_t_kernel(
    const __half* __restrict__ xpT, const float* __restrict__ wc,
    const float* __restrict__ bc, __half* __restrict__ uT) {
  const int idx = blockIdx.x * 256 + threadIdx.x;  // over DI * ROWS/4
  const int d = idx / (ROWS / 4);
  const int r4 = (idx - d * (ROWS / 4)) * 4;
  const int t0 = r4 % L_;
  const __half* row = xpT + (size_t)d * ROWS + r4;
  float v[4];
  load4h(row, v);
  float p0 = 0.f, p1 = 0.f, p2 = 0.f;
  if (t0 > 0) {
    p0 = __half2float(row[-3]);
    p1 = __half2float(row[-2]);
    p2 = __half2float(row[-1]);
  }
  const float w0 = wc[d * 4 + 0], w1 = wc[d * 4 + 1], w2 = wc[d * 4 + 2],
              w3 = wc[d * 4 + 3];
  const float bb = bc[d];
  float o[4];
  float s;
  s = bb + p0 * w0 + p1 * w1 + p2 * w2 + v[0] * w3; o[0] = s / (1.f + expf(-s));
  s = bb + p1 * w0 + p2 * w1 + v[0] * w2 + v[1] * w3; o[1] = s / (1.f + expf(-s));
  s = bb + p2 * w0 + v[0] * w1 + v[1] * w2 + v[2] * w3; o[2] = s / (1.f + expf(-s));
  s = bb + v[0] * w0 + v[1] * w1 + v[2] * w2 + v[3] * w3; o[3] = s / (1.f + expf(-s));
  union { __half2 h[2]; uint2 u; } pk;
  pk.h[0].x = __float2half(o[0]); pk.h[0].y = __float2half(o[1]);
  pk.h[1].x = __float2half(o[2]); pk.h[1].y = __float2half(o[3]);
  *(uint2*)(uT + (size_t)d * ROWS + r4) = pk.u;
}

// ---------------------------------------------------------------------------
// Selective scan v6: channel-major fp16 streams, deep LDS staging.
// 2048 one-wave blocks: 8 ch/wave (c=lane>>3), 2 states/lane (sg=lane&7).
// 32-step chunks via global_load_lds double-buffer:
//   instr1: lanes 0-31 dt, lanes 32-63 u  -> dtub[p][0..255 | 256..511]
//   instr2: lanes 0-31 z (32-63 scratch)  -> zbuf[p]
// B/C fp32 register-prefetched one 8-group ahead (L2-resident rows).
// y: register-buffered 8 steps -> 16B stores to channel-major yT (bf16).
// ---------------------------------------------------------------------------
__global__ __launch_bounds__(64) void scan_kernel(
    const __half* __restrict__ dtT, const __half* __restrict__ uT,
    const __half* __restrict__ zT, const float* __restrict__ xdblT,
    const float* __restrict__ A_log, const float* __restrict__ Dp,
    u16* __restrict__ yT) {
  __shared__ __align__(16) __half dtub[2][512];
  __shared__ __align__(16) __half zbuf[2][512];
  const int lane = threadIdx.x;
  const int b = blockIdx.x >> 8;           // 256 blocks per batch
  const int d0 = (blockIdx.x & 255) << 3;  // 8 channels/wave
  const int c = lane >> 3;
  const int sg = lane & 7;
  const int d = d0 + c;
  const int s0 = sg * 2;

  // staging mapping
  const int sl = lane & 31;
  const size_t srcoff =
      (size_t)(d0 + (sl >> 2)) * ROWS + (size_t)b * L_ + (sl & 3) * 8;
  const __half* gdtu = (lane < 32 ? dtT : uT) + srcoff;
  const __half* gz = zT + srcoff;

  const float2 Al = *(const float2*)(A_log + (size_t)d * DS + s0);
  const float A20 = -expf(Al.x) * 1.44269504f;
  const float A21 = -expf(Al.y) * 1.44269504f;
  const float Dpd = Dp[d];

  const float* Bp0 = xdblT + (size_t)(DR + s0) * ROWS + b * L_;
  const float* Bp1 = Bp0 + ROWS;
  const float* Cp0 = Bp0 + (size_t)DS * ROWS;
  const float* Cp1 = Cp0 + ROWS;
  u16* yp = yT + (size_t)d * ROWS + b * L_;

  float hs0 = 0.f, hs1 = 0.f;

  // stage chunk starting at t0 into buffer p
  auto stage = [&](int t0, int p) {
    __builtin_amdgcn_global_load_lds((gvoid_t*)(gdtu + t0),
                                     (lvoid_t*)&dtub[p][0], 16, 0, 0);
    __builtin_amdgcn_global_load_lds((gvoid_t*)(gz + t0),
                                     (lvoid_t*)&zbuf[p][0], 16, 0, 0);
  };

  stage(0, 0);
  float4 B0a = *(const float4*)Bp0, B0b = *(const float4*)(Bp0 + 4);
  float4 B1a = *(const float4*)Bp1, B1b = *(const float4*)(Bp1 + 4);
  float4 C0a = *(const float4*)Cp0, C0b = *(const float4*)(Cp0 + 4);
  float4 C1a = *(const float4*)Cp1, C1b = *(const float4*)(Cp1 + 4);

  for (int t0 = 0; t0 < L_; t0 += 8) {
    const int p = (t0 >> 5) & 1;
    if ((t0 & 31) == 0) {
      __builtin_amdgcn_s_waitcnt(0x0f70);  // vmcnt(0)
      __builtin_amdgcn_sched_barrier(0);
      if (t0 + 32 < L_) stage(t0 + 32, p ^ 1);
    }
    // prefetch next 8-group of B/C (overread past L_ lands in-bounds of ws)
    float4 nB0a = *(const float4*)(Bp0 + t0 + 8);
    float4 nB0b = *(const float4*)(Bp0 + t0 + 12);
    float4 nB1a = *(const float4*)(Bp1 + t0 + 8);
    float4 nB1b = *(const float4*)(Bp1 + t0 + 12);
    float4 nC0a = *(const float4*)(Cp0 + t0 + 8);
    float4 nC0b = *(const float4*)(Cp0 + t0 + 12);
    float4 nC1a = *(const float4*)(Cp1 + t0 + 8);
    float4 nC1b = *(const float4*)(Cp1 + t0 + 12);

    const int tl = t0 & 31;
    float dt8[8], u8[8];
    load4h(&dtub[p][c * 32 + tl], dt8);
    load4h(&dtub[p][c * 32 + tl + 4], dt8 + 4);
    load4h(&dtub[p][256 + c * 32 + tl], u8);
    load4h(&dtub[p][256 + c * 32 + tl + 4], u8 + 4);

    const float* B0v = (const float*)&B0a;  // B0a,B0b contiguous? use two ptrs
    const float* B0w = (const float*)&B0b;
    const float* B1v = (const float*)&B1a;
    const float* B1w = (const float*)&B1b;
    const float* C0v = (const float*)&C0a;
    const float* C0w = (const float*)&C0b;
    const float* C1v = (const float*)&C1a;
    const float* C1w = (const float*)&C1b;

    union { u16 h[8]; uint4 v; } yb;
#pragma unroll
    for (int k = 0; k < 8; k++) {
      const float dtv = dt8[k];
      const float uu = u8[k];
      const float du = dtv * uu;
      const float bb0 = (k < 4) ? B0v[k] : B0w[k - 4];
      const float bb1 = (k < 4) ? B1v[k] : B1w[k - 4];
      const float cc0 = (k < 4) ? C0v[k] : C0w[k - 4];
      const float cc1 = (k < 4) ? C1v[k] : C1w[k - 4];
      hs0 = fmaf(hs0, exp2f(dtv * A20), du * bb0);
      hs1 = fmaf(hs1, exp2f(dtv * A21), du * bb1);
      float pr = fmaf(hs1, cc1, hs0 * cc0);
      pr += __shfl_xor(pr, 1);
      pr += __shfl_xor(pr, 2);
      pr += __shfl_xor(pr, 4);
      if (sg == 0) {
        const float zz = __half2float(zbuf[p][c * 32 + tl + k]);
        float yv = pr + Dpd * uu;
        yv *= zz / (1.f + expf(-zz));
        yb.h[k] = f2bf(yv);
      }
    }
    if (sg == 0) *(uint4*)(yp + t0) = yb.v;
    B0a = nB0a; B0b = nB0b; B1a = nB1a; B1b = nB1b;
    C0a = nC0a; C0b = nC0b; C1a = nC1a; C1b = nC1b;
  }
}

// ---------------------------------------------------------------------------
// Final: rmsnorm(h[b, L-1, :]) @ w_fc + b_fc
// ---------------------------------------------------------------------------
__global__ __launch_bounds__(256) void final_kernel(
    const float* __restrict__ h, const float* __restrict__ fnw,
    const float* __restrict__ w_fc, const float* __restrict__ b_fc,
    float* __restrict__ out) {
  const int b = blockIdx.x;
  const int tid = threadIdx.x;
  const size_t row = ((size_t)b * L_ + (L_ - 1)) * DM;
  const float4 v = *(const float4*)(h + row + tid * 4);
  float ss = v.x * v.x + v.y * v.y + v.z * v.z + v.w * v.w;
#pragma unroll
  for (int off = 32; off > 0; off >>= 1) ss += __shfl_xor(ss, off);
  __shared__ float red[4];
  if ((tid & 63) == 0) red[tid >> 6] = ss;
  __syncthreads();
  float tot = red[0] + red[1] + red[2] + red[3];
  const float inv = rsqrtf(tot / (float)DM + EPS);
  const float4 wv = *(const float4*)(fnw + tid * 4);
  float hn[4] = {v.x * inv * wv.x, v.y * inv * wv.y, v.z * inv * wv.z,
                 v.w * inv * wv.w};
  float partial[NC];
#pragma unroll
  for (int j = 0; j < NC; j++) partial[j] = 0.f;
#pragma unroll
  for (int e = 0; e < 4; e++) {
    const int dd = tid * 4 + e;
#pragma unroll
    for (int j = 0; j < NC; j++)
      partial[j] = fmaf(hn[e], w_fc[dd * NC + j], partial[j]);
  }
  __shared__ float red2[256][NC];
  for (int j = 0; j < NC; j++) red2[tid][j] = partial[j];
  __syncthreads();
  for (int stride = 128; stride > 0; stride >>= 1) {
    if (tid < stride)
      for (int j = 0; j < NC; j++) red2[tid][j] += red2[tid + stride][j];
    __syncthreads();
  }
  if (tid < NC) out[b * NC + tid] = red2[0][tid] + b_fc[tid];
}

// ---------------------------------------------------------------------------
extern "C" void kernel_launch(void* const* d_in, const int* in_sizes, int n_in,
                              void* d_out, int out_size, void* d_ws,
                              size_t ws_size, hipStream_t stream) {
  const float* x = (const float*)d_in[0];
  const float* w_proj = (const float*)d_in[1];
  const float* b_proj = (const float*)d_in[2];
  const float* norm_w = (const float*)d_in[3];
  const float* w_in = (const float*)d_in[4];
  const float* w_conv = (const float*)d_in[5];
  const float* b_conv = (const float*)d_in[6];
  const float* w_x = (const float*)d_in[7];
  const float* w_dt = (const float*)d_in[8];
  const float* b_dt = (const float*)d_in[9];
  const float* A_log = (const float*)d_in[10];
  const float* Dp = (const float*)d_in[11];
  const float* w_out = (const float*)d_in[12];
  const float* fnw = (const float*)d_in[13];
  const float* w_fc = (const float*)d_in[14];
  const float* b_fc = (const float*)d_in[15];
  float* out = (float*)d_out;

  // Workspace layout (float units)
  float* ws = (float*)d_ws;
  float* h = ws;                              // 1,835,008
  __half* xzT = (__half*)(h + 1835008);       // [4096][1792] fp16 = 3,670,016 f
  __half* uT = (__half*)(h + 1835008 + 3670016);       // [2048][1792] fp16
  float* xdblT = h + 1835008 + 3670016 + 1835008;      // [96][1792] fp32
  __half* dtT = (__half*)(xdblT + 172032);             // [2048][1792] fp16
  float* nxt = xdblT + 172032 + 1835008;
  u16* yT = (u16*)nxt;                        // [2048][1792] bf16 = 1,835,008 f
  u16* y16 = (u16*)(nxt + 1835008);           // [1792][2048] bf16
  u16* xn16 = y16;                            // alias (disjoint liveness)
  u16* x16 = (u16*)(nxt + 3670016);           // 602,112 f
  u16* wprojT = (u16*)(nxt + 4272128);        // 344,064 f
  u16* winT = (u16*)(nxt + 4616192);          // 2,097,152 f
  u16* woutT = (u16*)(nxt + 6713344);         // 1,048,576 f
  float* w_xT = nxt + 7761920;                // [96][2048] 196,608 f
  float* w_dtT = w_xT + 196608;               // [2048][64] 131,072 f
  // w_dtT directly after w_xT: the M-guarded w_x GEMM overreads A rows
  // 96..127, which land harmlessly in w_dtT.

  const dim3 blk(256);

  cvt_kernel<<<ROWS * DLOC / 1024, blk, 0, stream>>>(x, x16);
  transpose_cvt_kernel<<<dim3(DM / 32, DLOC / 32), blk, 0, stream>>>(
      w_proj, wprojT, DLOC, DM);

  // h = x @ w_proj + b_proj (bf16 MFMA, row-major fp32 out)
  gemm_bt_mfma<0, 1, 0><<<dim3(DM / 128, ROWS / 128), blk, 0, stream>>>(
      x16, wprojT, b_proj, h, DLOC, DLOC, DLOC, DM);

  for (int l = 0; l < NL; l++) {
    transpose_cvt_kernel<<<dim3(2 * DI / 32, DM / 32), blk, 0, stream>>>(
        w_in + (size_t)l * DM * 2 * DI, winT, DM, 2 * DI);
    transpose_cvt_kernel<<<dim3(DM / 32, DI / 32), blk, 0, stream>>>(
        w_out + (size_t)l * DI * DM, woutT, DI, DM);
    transpose_f32_kernel<<<dim3(96 / 32, DI / 32), blk, 0, stream>>>(
        w_x + (size_t)l * DI * 96, w_xT, DI, 96);
    transpose_f32_kernel<<<dim3(DI / 32, DR / 32), blk, 0, stream>>>(
        w_dt + (size_t)l * DR * DI, w_dtT, DR, DI);

    // xn = rmsnorm(h) -> bf16
    rmsnorm_kernel<<<ROWS, blk, 0, stream>>>(h, norm_w + (size_t)l * DM, xn16);
    // xzT[4096][1792] = (xn @ w_in[l])^T  (MFMA, fp16 transposed store)
    gemm_bt_mfma<0, 0, 1><<<dim3(2 * DI / 128, ROWS / 128), blk, 0, stream>>>(
        xn16, winT, nullptr, (float*)xzT, DM, DM, DM, ROWS);
    // uT = silu(conv(xpT) + b_conv), fp16 channel-major
    conv_silu_t_kernel<<<DI * (ROWS / 4) / 256, blk, 0, stream>>>(
        xzT, w_conv + (size_t)l * DI * DC, b_conv + (size_t)l * DI, uT);
    // xdblT[96][1792] = w_xT @ uT  (fp32 acc, fp16 B, split-K x8 + atomics)
    hipMemsetAsync(xdblT, 0, (size_t)96 * ROWS * sizeof(float), stream);
    gemm_kernel<2, 0, 1, 0, __half, float>
        <<<dim3(ROWS / 64, 2, 8), blk, 0, stream>>>(
            w_xT, uT, nullptr, xdblT, 96, ROWS, 256, DI, ROWS, ROWS);
    // dtT[2048][1792] = softplus(w_dtT @ dtrT + b_dt[m]) -> fp16
    gemm_kernel<0, 1, 0, 2, float, __half>
        <<<dim3(ROWS / 64, DI / 64), blk, 0, stream>>>(
            w_dtT, xdblT, b_dt + (size_t)l * DI, dtT, DI, ROWS, DR, DR, ROWS,
            ROWS);
    // yT[2048][1792] = scan(...)  (2048 one-wave blocks)
    scan_kernel<<<B_ * (DI / 8), dim3(64), 0, stream>>>(
        dtT, uT, xzT + (size_t)DI * ROWS, xdblT, A_log + (size_t)l * DI * DS,
        Dp + (size_t)l * DI, yT);
    // y16[1792][2048] = yT^T
    transpose_u16_kernel<<<dim3(ROWS / 32, DI / 32), blk, 0, stream>>>(
        yT, y16, DI, ROWS);
    // h += y @ w_out[l]  (MFMA)
    gemm_bt_mfma<1, 0, 0><<<dim3(DM / 128, ROWS / 128), blk, 0, stream>>>(
        y16, woutT, nullptr, h, DI, DI, DI, DM);
  }

  final_kernel<<<B_, blk, 0, stream>>>(h, fnw, w_fc, b_fc, out);
}

// Round 7
// 1143.590 us; speedup vs baseline: 1.1419x; 1.0895x over previous
//
#include <hip/hip_runtime.h>
#include <hip/hip_bf16.h>
#include <hip/hip_fp16.h>
#include <math.h>

#define NL 4
#define DM 1024
#define DI 2048
#define DS 16
#define DR 64
#define DC 4
#define B_ 8
#define L_ 224
#define DLOC 672
#define NC 10
#define EPS 1e-5f

#define ROWS (B_ * L_)  // 1792

typedef unsigned short u16;
typedef __attribute__((ext_vector_type(8))) short bf16x8;
typedef __attribute__((ext_vector_type(4))) float f32x4;
typedef __attribute__((address_space(1))) const void gvoid_t;
typedef __attribute__((address_space(3))) void lvoid_t;

__device__ __forceinline__ u16 f2bf(float f) {
  union { float f; unsigned int u; } v;
  v.f = f;
  unsigned int u = v.u;
  return (u16)((u + 0x7fffu + ((u >> 16) & 1u)) >> 16);  // RNE
}

// load 4 consecutive halfs (8B aligned) -> 4 floats
__device__ __forceinline__ void load4h(const __half* p, float* o) {
  uint2 r = *(const uint2*)p;
  __half2 h0 = *(__half2*)&r.x;
  __half2 h1 = *(__half2*)&r.y;
  float2 f0 = __half22float2(h0);
  float2 f1 = __half22float2(h1);
  o[0] = f0.x; o[1] = f0.y; o[2] = f1.x; o[3] = f1.y;
}

// load 8 consecutive halfs (16B aligned) -> 8 floats (single ds_read_b128)
__device__ __forceinline__ void load8h(const __half* p, float* o) {
  uint4 r = *(const uint4*)p;
  __half2 h0 = *(__half2*)&r.x;
  __half2 h1 = *(__half2*)&r.y;
  __half2 h2 = *(__half2*)&r.z;
  __half2 h3 = *(__half2*)&r.w;
  float2 f0 = __half22float2(h0);
  float2 f1 = __half22float2(h1);
  float2 f2 = __half22float2(h2);
  float2 f3 = __half22float2(h3);
  o[0] = f0.x; o[1] = f0.y; o[2] = f1.x; o[3] = f1.y;
  o[4] = f2.x; o[5] = f2.y; o[6] = f3.x; o[7] = f3.y;
}

// ---------------------------------------------------------------------------
// bf16 MFMA GEMM: C[M,N](+)=A[M,K]_bf16 @ Bt[N,K]_bf16^T. 128x128 tile.
// TSTORE=1: store C^T as fp16 (ldc = leading dim of transposed output).
// ---------------------------------------------------------------------------
template <int ACC, int BIAS, int TSTORE>
__global__ __launch_bounds__(256) void gemm_bt_mfma(
    const u16* __restrict__ A, const u16* __restrict__ Bt,
    const float* __restrict__ bias, float* __restrict__ C, int K, int lda,
    int ldb, int ldc) {
  __shared__ __align__(16) u16 As[128 * 32];
  __shared__ __align__(16) u16 Bs[128 * 32];
  const int tid = threadIdx.x;
  const int lane = tid & 63;
  const int wv = tid >> 6;
  const int n0 = blockIdx.x * 128;
  const int m0 = blockIdx.y * 128;
  const int wm0 = (wv & 1) * 64;
  const int wn0 = (wv >> 1) * 64;
  const int quad = lane >> 4;
  const int l16 = lane & 15;

  const int srow = wv * 32 + (lane >> 2);
  const int scol = (lane & 3) * 8;
  const u16* ga0 = A + (size_t)(m0 + srow) * lda + scol;
  const u16* ga1 = ga0 + (size_t)16 * lda;
  const u16* gb0 = Bt + (size_t)(n0 + srow) * ldb + scol;
  const u16* gb1 = gb0 + (size_t)16 * ldb;
  u16* la0 = &As[(wv * 32) * 32];
  u16* la1 = &As[(wv * 32 + 16) * 32];
  u16* lb0 = &Bs[(wv * 32) * 32];
  u16* lb1 = &Bs[(wv * 32 + 16) * 32];

  f32x4 acc[4][4] = {};

  for (int k0 = 0; k0 < K; k0 += 32) {
    __syncthreads();
    __builtin_amdgcn_global_load_lds((gvoid_t*)ga0, (lvoid_t*)la0, 16, 0, 0);
    __builtin_amdgcn_global_load_lds((gvoid_t*)ga1, (lvoid_t*)la1, 16, 0, 0);
    __builtin_amdgcn_global_load_lds((gvoid_t*)gb0, (lvoid_t*)lb0, 16, 0, 0);
    __builtin_amdgcn_global_load_lds((gvoid_t*)gb1, (lvoid_t*)lb1, 16, 0, 0);
    __syncthreads();
    bf16x8 af[4], bfr[4];
#pragma unroll
    for (int i = 0; i < 4; i++)
      af[i] = *(const bf16x8*)&As[(wm0 + i * 16 + l16) * 32 + quad * 8];
#pragma unroll
    for (int j = 0; j < 4; j++)
      bfr[j] = *(const bf16x8*)&Bs[(wn0 + j * 16 + l16) * 32 + quad * 8];
#pragma unroll
    for (int i = 0; i < 4; i++)
#pragma unroll
      for (int j = 0; j < 4; j++)
        acc[i][j] = __builtin_amdgcn_mfma_f32_16x16x32_bf16(af[i], bfr[j],
                                                            acc[i][j], 0, 0, 0);
    ga0 += 32; ga1 += 32; gb0 += 32; gb1 += 32;
  }

#pragma unroll
  for (int i = 0; i < 4; i++) {
#pragma unroll
    for (int j = 0; j < 4; j++) {
      const int col = n0 + wn0 + j * 16 + l16;
      const int rowb = m0 + wm0 + i * 16 + quad * 4;
      if (TSTORE) {
        __half* Ch = (__half*)C;
        __half2 p0, p1;
        p0.x = __float2half(acc[i][j][0]); p0.y = __float2half(acc[i][j][1]);
        p1.x = __float2half(acc[i][j][2]); p1.y = __float2half(acc[i][j][3]);
        union { __half2 h[2]; uint2 u; } pk;
        pk.h[0] = p0; pk.h[1] = p1;
        *(uint2*)(Ch + (size_t)col * ldc + rowb) = pk.u;
      } else {
        float bv = 0.f;
        if (BIAS) bv = bias[col];
#pragma unroll
        for (int r = 0; r < 4; r++) {
          float v = acc[i][j][r] + bv;
          float* p = C + (size_t)(rowb + r) * ldc + col;
          if (ACC) v += *p;
          *p = v;
        }
      }
    }
  }
}

// ---------------------------------------------------------------------------
// fp32-accum tiled GEMM, templated operand/output types.
// ACC: 0=store, 2=atomicAdd(float). ACT 1 = softplus. BROW: 0 none, 2 bias[m].
// ---------------------------------------------------------------------------
template <int ACC, int ACT, int SPLITK, int BROW, typename BT, typename OT>
__global__ __launch_bounds__(256) void gemm_kernel(
    const float* __restrict__ A, const BT* __restrict__ Bm,
    const float* __restrict__ bias, OT* __restrict__ C, int M, int N, int K,
    int lda, int ldb, int ldc) {
  if (SPLITK) {
    A += (size_t)blockIdx.z * 256;
    Bm += (size_t)blockIdx.z * 256 * ldb;
  }
  __shared__ float As[16][64];
  __shared__ float Bs[16][64];
  const int tid = threadIdx.x;
  const int tx = tid & 15;
  const int ty = tid >> 4;
  const int n0 = blockIdx.x * 64;
  const int m0 = blockIdx.y * 64;
  const int am = tid & 63;
  const int ak = (tid >> 6) * 4;
  const int bk = tid >> 4;
  const int bn = (tid & 15) * 4;

  float acc[4][4];
#pragma unroll
  for (int i = 0; i < 4; i++)
#pragma unroll
    for (int j = 0; j < 4; j++) acc[i][j] = 0.f;

  for (int k0 = 0; k0 < K; k0 += 16) {
    float4 av = *(const float4*)(A + (size_t)(m0 + am) * lda + k0 + ak);
    float4 bv;
    {
      int n = n0 + bn;
      const BT* bp = Bm + (size_t)(k0 + bk) * ldb + n;
      if (n + 3 < N) {
        if (sizeof(BT) == 2) {
          load4h((const __half*)bp, (float*)&bv);
        } else {
          bv = *(const float4*)(const void*)bp;
        }
      } else {
        bv.x = (n + 0 < N) ? (float)bp[0] : 0.f;
        bv.y = (n + 1 < N) ? (float)bp[1] : 0.f;
        bv.z = (n + 2 < N) ? (float)bp[2] : 0.f;
        bv.w = (n + 3 < N) ? (float)bp[3] : 0.f;
      }
    }
    __syncthreads();
    As[ak + 0][am] = av.x;
    As[ak + 1][am] = av.y;
    As[ak + 2][am] = av.z;
    As[ak + 3][am] = av.w;
    *(float4*)(&Bs[bk][bn]) = bv;
    __syncthreads();
#pragma unroll
    for (int kk = 0; kk < 16; kk++) {
      float4 a4 = *(const float4*)(&As[kk][ty * 4]);
      float4 b4 = *(const float4*)(&Bs[kk][tx * 4]);
      float ar[4] = {a4.x, a4.y, a4.z, a4.w};
      float br[4] = {b4.x, b4.y, b4.z, b4.w};
#pragma unroll
      for (int i = 0; i < 4; i++)
#pragma unroll
        for (int j = 0; j < 4; j++) acc[i][j] = fmaf(ar[i], br[j], acc[i][j]);
    }
  }

#pragma unroll
  for (int i = 0; i < 4; i++) {
    int m = m0 + ty * 4 + i;
#pragma unroll
    for (int j = 0; j < 4; j++) {
      int n = n0 + tx * 4 + j;
      if (n < N && m < M) {
        float v = acc[i][j];
        if (BROW == 2) v += bias[m];
        if (ACT == 1) v = (v > 20.f) ? v : log1pf(expf(v));  // softplus
        OT* p = C + (size_t)m * ldc + n;
        if (ACC == 2) {
          atomicAdd((float*)p, v);
        } else {
          *p = (OT)v;
        }
      }
    }
  }
}

// ---------------------------------------------------------------------------
// fp32 [K,N] -> bf16 [N,K] transpose+convert
// ---------------------------------------------------------------------------
__global__ __launch_bounds__(256) void transpose_cvt_kernel(
    const float* __restrict__ src, u16* __restrict__ dst, int K, int N) {
  __shared__ float t[32][33];
  const int n0 = blockIdx.x * 32;
  const int k0 = blockIdx.y * 32;
  const int c = threadIdx.x & 31;
  const int r = threadIdx.x >> 5;
#pragma unroll
  for (int rr = 0; rr < 4; rr++)
    t[r + rr * 8][c] = src[(size_t)(k0 + r + rr * 8) * N + n0 + c];
  __syncthreads();
#pragma unroll
  for (int rr = 0; rr < 4; rr++)
    dst[(size_t)(n0 + r + rr * 8) * K + k0 + c] = f2bf(t[c][r + rr * 8]);
}

// fp32 [K,N] -> fp32 [N,K]
__global__ __launch_bounds__(256) void transpose_f32_kernel(
    const float* __restrict__ src, float* __restrict__ dst, int K, int N) {
  __shared__ float t[32][33];
  const int n0 = blockIdx.x * 32;
  const int k0 = blockIdx.y * 32;
  const int c = threadIdx.x & 31;
  const int r = threadIdx.x >> 5;
#pragma unroll
  for (int rr = 0; rr < 4; rr++)
    t[r + rr * 8][c] = src[(size_t)(k0 + r + rr * 8) * N + n0 + c];
  __syncthreads();
#pragma unroll
  for (int rr = 0; rr < 4; rr++)
    dst[(size_t)(n0 + r + rr * 8) * K + k0 + c] = t[c][r + rr * 8];
}

// u16 [K,N] -> u16 [N,K]  (yT -> y row-major)
__global__ __launch_bounds__(256) void transpose_u16_kernel(
    const u16* __restrict__ src, u16* __restrict__ dst, int K, int N) {
  __shared__ u16 t[32][33];
  const int n0 = blockIdx.x * 32;
  const int k0 = blockIdx.y * 32;
  const int c = threadIdx.x & 31;
  const int r = threadIdx.x >> 5;
#pragma unroll
  for (int rr = 0; rr < 4; rr++)
    t[r + rr * 8][c] = src[(size_t)(k0 + r + rr * 8) * N + n0 + c];
  __syncthreads();
#pragma unroll
  for (int rr = 0; rr < 4; rr++)
    dst[(size_t)(n0 + r + rr * 8) * K + k0 + c] = t[c][r + rr * 8];
}

// flat fp32 -> bf16
__global__ __launch_bounds__(256) void cvt_kernel(const float* __restrict__ src,
                                                  u16* __restrict__ dst) {
  const int i = blockIdx.x * 256 + threadIdx.x;
  const float4 v = ((const float4*)src)[i];
  ushort4 o;
  o.x = f2bf(v.x);
  o.y = f2bf(v.y);
  o.z = f2bf(v.z);
  o.w = f2bf(v.w);
  ((ushort4*)dst)[i] = o;
}

// ---------------------------------------------------------------------------
// RMSNorm -> bf16
// ---------------------------------------------------------------------------
__global__ __launch_bounds__(256) void rmsnorm_kernel(
    const float* __restrict__ h, const float* __restrict__ w,
    u16* __restrict__ out) {
  const int row = blockIdx.x;
  const int tid = threadIdx.x;
  const float4 v = *(const float4*)(h + (size_t)row * DM + tid * 4);
  float ss = v.x * v.x + v.y * v.y + v.z * v.z + v.w * v.w;
#pragma unroll
  for (int off = 32; off > 0; off >>= 1) ss += __shfl_xor(ss, off);
  __shared__ float red[4];
  if ((tid & 63) == 0) red[tid >> 6] = ss;
  __syncthreads();
  float tot = red[0] + red[1] + red[2] + red[3];
  const float inv = rsqrtf(tot / (float)DM + EPS);
  const float4 wv = *(const float4*)(w + tid * 4);
  ushort4 o;
  o.x = f2bf(v.x * inv * wv.x);
  o.y = f2bf(v.y * inv * wv.y);
  o.z = f2bf(v.z * inv * wv.z);
  o.w = f2bf(v.w * inv * wv.w);
  *(ushort4*)(out + (size_t)row * DM + tid * 4) = o;
}

// ---------------------------------------------------------------------------
// Causal depthwise conv + bias + silu, channel-major fp16 -> fp16
// ---------------------------------------------------------------------------
__global__ __launch_bounds__(256) void conv_silu_t_kernel(
    const __half* __restrict__ xpT, const float* __restrict__ wc,
    const float* __restrict__ bc, __half* __restrict__ uT) {
  const int idx = blockIdx.x * 256 + threadIdx.x;  // over DI * ROWS/4
  const int d = idx / (ROWS / 4);
  const int r4 = (idx - d * (ROWS / 4)) * 4;
  const int t0 = r4 % L_;
  const __half* row = xpT + (size_t)d * ROWS + r4;
  float v[4];
  load4h(row, v);
  float p0 = 0.f, p1 = 0.f, p2 = 0.f;
  if (t0 > 0) {
    p0 = __half2float(row[-3]);
    p1 = __half2float(row[-2]);
    p2 = __half2float(row[-1]);
  }
  const float w0 = wc[d * 4 + 0], w1 = wc[d * 4 + 1], w2 = wc[d * 4 + 2],
              w3 = wc[d * 4 + 3];
  const float bb = bc[d];
  float o[4];
  float s;
  s = bb + p0 * w0 + p1 * w1 + p2 * w2 + v[0] * w3; o[0] = s / (1.f + expf(-s));
  s = bb + p1 * w0 + p2 * w1 + v[0] * w2 + v[1] * w3; o[1] = s / (1.f + expf(-s));
  s = bb + p2 * w0 + v[0] * w1 + v[1] * w2 + v[2] * w3; o[2] = s / (1.f + expf(-s));
  s = bb + v[0] * w0 + v[1] * w1 + v[2] * w2 + v[3] * w3; o[3] = s / (1.f + expf(-s));
  union { __half2 h[2]; uint2 u; } pk;
  pk.h[0].x = __float2half(o[0]); pk.h[0].y = __float2half(o[1]);
  pk.h[1].x = __float2half(o[2]); pk.h[1].y = __float2half(o[3]);
  *(uint2*)(uT + (size_t)d * ROWS + r4) = pk.u;
}

// ---------------------------------------------------------------------------
// Selective scan v7: 4-wave blocks, block-shared B/C LDS, conflict-free
// dt/u/z staging. 512 blocks x 256 thr; block = (batch, 32 channels);
// wave = 8 channels, lane = (c<<3)|sg, states {2sg,2sg+1} per lane.
// Per 32-step chunk:
//  - dt/u per wave: one global_load_lds (lanes 0-31 dt, 32-63 u), piece
//    order [tblk][c] -> per-8-step reads are single conflict-free b128.
//  - z same (lanes 32-63 duplicate harmlessly).
//  - B/C: cooperative float4 global load + padded ds_write (stride 36),
//    double-buffered, __syncthreads per chunk.
// ---------------------------------------------------------------------------
__global__ __launch_bounds__(256) void scan_kernel(
    const __half* __restrict__ dtT, const __half* __restrict__ uT,
    const __half* __restrict__ zT, const float* __restrict__ xdblT,
    const float* __restrict__ A_log, const float* __restrict__ Dp,
    u16* __restrict__ yT) {
  __shared__ __align__(16) __half dtu[4][2][512];
  __shared__ __align__(16) __half zbuf[4][2][512];
  __shared__ __align__(16) float bcb[2][32 * 36];

  const int tid = threadIdx.x;
  const int wv = tid >> 6;
  const int lane = tid & 63;
  const int b = blockIdx.x >> 6;            // 64 blocks per batch
  const int d0 = ((blockIdx.x & 63) << 5) + wv * 8;
  const int c = lane >> 3;
  const int sg = lane & 7;
  const int d = d0 + c;
  const int s0 = sg * 2;

  // dt/u/z staging lane mapping: piece sl -> (c = sl&7, tblk = sl>>3)
  const int sl = lane & 31;
  const size_t srcoff =
      (size_t)(d0 + (sl & 7)) * ROWS + (size_t)b * L_ + (sl >> 3) * 8;
  const __half* gdtu = (lane < 32 ? dtT : uT) + srcoff;
  const __half* gz = zT + srcoff;

  // B/C cooperative staging mapping: thread -> (s-row, 4 t's)
  const int bs = tid >> 3;              // 0..31 (B rows 0-15, C rows 16-31)
  const int bt4 = (tid & 7) * 4;
  const float* gbc = xdblT + (size_t)(DR + bs) * ROWS + (size_t)b * L_ + bt4;

  const float2 Al = *(const float2*)(A_log + (size_t)d * DS + s0);
  const float A20 = -expf(Al.x) * 1.44269504f;
  const float A21 = -expf(Al.y) * 1.44269504f;
  const float Dpd = Dp[d];
  u16* yp = yT + (size_t)d * ROWS + b * L_;

  float hs0 = 0.f, hs1 = 0.f;

  auto stage_dtuz = [&](int t0, int p) {
    __builtin_amdgcn_global_load_lds((gvoid_t*)(gdtu + t0),
                                     (lvoid_t*)&dtu[wv][p][0], 16, 0, 0);
    __builtin_amdgcn_global_load_lds((gvoid_t*)(gz + t0),
                                     (lvoid_t*)&zbuf[wv][p][0], 16, 0, 0);
  };

  // prologue: stage chunk 0 fully
  {
    float4 bc0 = *(const float4*)gbc;
    stage_dtuz(0, 0);
    __builtin_amdgcn_s_waitcnt(0x0f70);  // vmcnt(0)
    *(float4*)&bcb[0][bs * 36 + bt4] = bc0;
    __syncthreads();
  }

  for (int ch = 0; ch < L_ / 32; ch++) {
    const int p = ch & 1;
    const int t0 = ch * 32;
    float4 bcn;
    const bool more = (ch + 1 < L_ / 32);
    if (more) {
      bcn = *(const float4*)(gbc + t0 + 32);
      stage_dtuz(t0 + 32, p ^ 1);
    }
#pragma unroll
    for (int g = 0; g < 4; g++) {  // 4 groups of 8 steps
      float dt8[8], u8[8], z8[8];
      load8h(&dtu[wv][p][g * 64 + c * 8], dt8);
      load8h(&dtu[wv][p][256 + g * 64 + c * 8], u8);
      load8h(&zbuf[wv][p][g * 64 + c * 8], z8);
      union { u16 h[8]; uint4 v; } yb;
#pragma unroll
      for (int k = 0; k < 8; k++) {
        const int tt = g * 8 + k;
        const float Bv0 = bcb[p][s0 * 36 + tt];
        const float Bv1 = bcb[p][(s0 + 1) * 36 + tt];
        const float Cv0 = bcb[p][(16 + s0) * 36 + tt];
        const float Cv1 = bcb[p][(17 + s0) * 36 + tt];
        const float dtv = dt8[k];
        const float uu = u8[k];
        const float du = dtv * uu;
        hs0 = fmaf(hs0, exp2f(dtv * A20), du * Bv0);
        hs1 = fmaf(hs1, exp2f(dtv * A21), du * Bv1);
        float pr = fmaf(hs1, Cv1, hs0 * Cv0);
        pr += __shfl_xor(pr, 1);
        pr += __shfl_xor(pr, 2);
        pr += __shfl_xor(pr, 4);
        if (sg == 0) {
          const float zz = z8[k];
          float yv = pr + Dpd * uu;
          yv *= zz / (1.f + expf(-zz));
          yb.h[k] = f2bf(yv);
        }
      }
      if (sg == 0) *(uint4*)(yp + t0 + g * 8) = yb.v;
    }
    if (more) {
      __builtin_amdgcn_s_waitcnt(0x0f70);  // vmcnt(0): bcn + dtuz staged
      *(float4*)&bcb[p ^ 1][bs * 36 + bt4] = bcn;
    }
    __syncthreads();
  }
}

// ---------------------------------------------------------------------------
// Final: rmsnorm(h[b, L-1, :]) @ w_fc + b_fc
// ---------------------------------------------------------------------------
__global__ __launch_bounds__(256) void final_kernel(
    const float* __restrict__ h, const float* __restrict__ fnw,
    const float* __restrict__ w_fc, const float* __restrict__ b_fc,
    float* __restrict__ out) {
  const int b = blockIdx.x;
  const int tid = threadIdx.x;
  const size_t row = ((size_t)b * L_ + (L_ - 1)) * DM;
  const float4 v = *(const float4*)(h + row + tid * 4);
  float ss = v.x * v.x + v.y * v.y + v.z * v.z + v.w * v.w;
#pragma unroll
  for (int off = 32; off > 0; off >>= 1) ss += __shfl_xor(ss, off);
  __shared__ float red[4];
  if ((tid & 63) == 0) red[tid >> 6] = ss;
  __syncthreads();
  float tot = red[0] + red[1] + red[2] + red[3];
  const float inv = rsqrtf(tot / (float)DM + EPS);
  const float4 wv = *(const float4*)(fnw + tid * 4);
  float hn[4] = {v.x * inv * wv.x, v.y * inv * wv.y, v.z * inv * wv.z,
                 v.w * inv * wv.w};
  float partial[NC];
#pragma unroll
  for (int j = 0; j < NC; j++) partial[j] = 0.f;
#pragma unroll
  for (int e = 0; e < 4; e++) {
    const int dd = tid * 4 + e;
#pragma unroll
    for (int j = 0; j < NC; j++)
      partial[j] = fmaf(hn[e], w_fc[dd * NC + j], partial[j]);
  }
  __shared__ float red2[256][NC];
  for (int j = 0; j < NC; j++) red2[tid][j] = partial[j];
  __syncthreads();
  for (int stride = 128; stride > 0; stride >>= 1) {
    if (tid < stride)
      for (int j = 0; j < NC; j++) red2[tid][j] += red2[tid + stride][j];
    __syncthreads();
  }
  if (tid < NC) out[b * NC + tid] = red2[0][tid] + b_fc[tid];
}

// ---------------------------------------------------------------------------
extern "C" void kernel_launch(void* const* d_in, const int* in_sizes, int n_in,
                              void* d_out, int out_size, void* d_ws,
                              size_t ws_size, hipStream_t stream) {
  const float* x = (const float*)d_in[0];
  const float* w_proj = (const float*)d_in[1];
  const float* b_proj = (const float*)d_in[2];
  const float* norm_w = (const float*)d_in[3];
  const float* w_in = (const float*)d_in[4];
  const float* w_conv = (const float*)d_in[5];
  const float* b_conv = (const float*)d_in[6];
  const float* w_x = (const float*)d_in[7];
  const float* w_dt = (const float*)d_in[8];
  const float* b_dt = (const float*)d_in[9];
  const float* A_log = (const float*)d_in[10];
  const float* Dp = (const float*)d_in[11];
  const float* w_out = (const float*)d_in[12];
  const float* fnw = (const float*)d_in[13];
  const float* w_fc = (const float*)d_in[14];
  const float* b_fc = (const float*)d_in[15];
  float* out = (float*)d_out;

  // Workspace layout (float units)
  float* ws = (float*)d_ws;
  float* h = ws;                              // 1,835,008
  __half* xzT = (__half*)(h + 1835008);       // [4096][1792] fp16 = 3,670,016 f
  __half* uT = (__half*)(h + 1835008 + 3670016);       // [2048][1792] fp16
  float* xdblT = h + 1835008 + 3670016 + 1835008;      // [96][1792] fp32
  __half* dtT = (__half*)(xdblT + 172032);             // [2048][1792] fp16
  float* nxt = xdblT + 172032 + 1835008;
  u16* yT = (u16*)nxt;                        // [2048][1792] bf16 = 1,835,008 f
  u16* y16 = (u16*)(nxt + 1835008);           // [1792][2048] bf16
  u16* xn16 = y16;                            // alias (disjoint liveness)
  u16* x16 = (u16*)(nxt + 3670016);           // 602,112 f
  u16* wprojT = (u16*)(nxt + 4272128);        // 344,064 f
  u16* winT = (u16*)(nxt + 4616192);          // 2,097,152 f
  u16* woutT = (u16*)(nxt + 6713344);         // 1,048,576 f
  float* w_xT = nxt + 7761920;                // [96][2048] 196,608 f
  float* w_dtT = w_xT + 196608;               // [2048][64] 131,072 f
  // w_dtT directly after w_xT: the M-guarded w_x GEMM overreads A rows
  // 96..127, which land harmlessly in w_dtT.

  const dim3 blk(256);

  cvt_kernel<<<ROWS * DLOC / 1024, blk, 0, stream>>>(x, x16);
  transpose_cvt_kernel<<<dim3(DM / 32, DLOC / 32), blk, 0, stream>>>(
      w_proj, wprojT, DLOC, DM);

  // h = x @ w_proj + b_proj (bf16 MFMA, row-major fp32 out)
  gemm_bt_mfma<0, 1, 0><<<dim3(DM / 128, ROWS / 128), blk, 0, stream>>>(
      x16, wprojT, b_proj, h, DLOC, DLOC, DLOC, DM);

  for (int l = 0; l < NL; l++) {
    transpose_cvt_kernel<<<dim3(2 * DI / 32, DM / 32), blk, 0, stream>>>(
        w_in + (size_t)l * DM * 2 * DI, winT, DM, 2 * DI);
    transpose_cvt_kernel<<<dim3(DM / 32, DI / 32), blk, 0, stream>>>(
        w_out + (size_t)l * DI * DM, woutT, DI, DM);
    transpose_f32_kernel<<<dim3(96 / 32, DI / 32), blk, 0, stream>>>(
        w_x + (size_t)l * DI * 96, w_xT, DI, 96);
    transpose_f32_kernel<<<dim3(DI / 32, DR / 32), blk, 0, stream>>>(
        w_dt + (size_t)l * DR * DI, w_dtT, DR, DI);

    // xn = rmsnorm(h) -> bf16
    rmsnorm_kernel<<<ROWS, blk, 0, stream>>>(h, norm_w + (size_t)l * DM, xn16);
    // xzT[4096][1792] = (xn @ w_in[l])^T  (MFMA, fp16 transposed store)
    gemm_bt_mfma<0, 0, 1><<<dim3(2 * DI / 128, ROWS / 128), blk, 0, stream>>>(
        xn16, winT, nullptr, (float*)xzT, DM, DM, DM, ROWS);
    // uT = silu(conv(xpT) + b_conv), fp16 channel-major
    conv_silu_t_kernel<<<DI * (ROWS / 4) / 256, blk, 0, stream>>>(
        xzT, w_conv + (size_t)l * DI * DC, b_conv + (size_t)l * DI, uT);
    // xdblT[96][1792] = w_xT @ uT  (fp32 acc, fp16 B, split-K x8 + atomics)
    hipMemsetAsync(xdblT, 0, (size_t)96 * ROWS * sizeof(float), stream);
    gemm_kernel<2, 0, 1, 0, __half, float>
        <<<dim3(ROWS / 64, 2, 8), blk, 0, stream>>>(
            w_xT, uT, nullptr, xdblT, 96, ROWS, 256, DI, ROWS, ROWS);
    // dtT[2048][1792] = softplus(w_dtT @ dtrT + b_dt[m]) -> fp16
    gemm_kernel<0, 1, 0, 2, float, __half>
        <<<dim3(ROWS / 64, DI / 64), blk, 0, stream>>>(
            w_dtT, xdblT, b_dt + (size_t)l * DI, dtT, DI, ROWS, DR, DR, ROWS,
            ROWS);
    // yT[2048][1792] = scan(...)  (512 blocks x 4 waves)
    scan_kernel<<<dim3(B_ * (DI / 32)), blk, 0, stream>>>(
        dtT, uT, xzT + (size_t)DI * ROWS, xdblT, A_log + (size_t)l * DI * DS,
        Dp + (size_t)l * DI, yT);
    // y16[1792][2048] = yT^T
    transpose_u16_kernel<<<dim3(ROWS / 32, DI / 32), blk, 0, stream>>>(
        yT, y16, DI, ROWS);
    // h += y @ w_out[l]  (MFMA)
    gemm_bt_mfma<1, 0, 0><<<dim3(DM / 128, ROWS / 128), blk, 0, stream>>>(
        y16, woutT, nullptr, h, DI, DI, DI, DM);
  }

  final_kernel<<<B_, blk, 0, stream>>>(h, fnw, w_fc, b_fc, out);
}

// Round 8
// 1072.632 us; speedup vs baseline: 1.2174x; 1.0662x over previous
//
#include <hip/hip_runtime.h>
#include <hip/hip_bf16.h>
#include <hip/hip_fp16.h>
#include <math.h>

#define NL 4
#define DM 1024
#define DI 2048
#define DS 16
#define DR 64
#define DC 4
#define B_ 8
#define L_ 224
#define DLOC 672
#define NC 10
#define EPS 1e-5f

#define ROWS (B_ * L_)  // 1792

typedef unsigned short u16;
typedef __attribute__((ext_vector_type(8))) short bf16x8;
typedef __attribute__((ext_vector_type(4))) float f32x4;
typedef __attribute__((address_space(1))) const void gvoid_t;
typedef __attribute__((address_space(3))) void lvoid_t;

__device__ __forceinline__ u16 f2bf(float f) {
  union { float f; unsigned int u; } v;
  v.f = f;
  unsigned int u = v.u;
  return (u16)((u + 0x7fffu + ((u >> 16) & 1u)) >> 16);  // RNE
}

// load 4 consecutive halfs (8B aligned) -> 4 floats
__device__ __forceinline__ void load4h(const __half* p, float* o) {
  uint2 r = *(const uint2*)p;
  __half2 h0 = *(__half2*)&r.x;
  __half2 h1 = *(__half2*)&r.y;
  float2 f0 = __half22float2(h0);
  float2 f1 = __half22float2(h1);
  o[0] = f0.x; o[1] = f0.y; o[2] = f1.x; o[3] = f1.y;
}

// load 8 consecutive halfs (16B aligned) -> 8 floats (single ds_read_b128)
__device__ __forceinline__ void load8h(const __half* p, float* o) {
  uint4 r = *(const uint4*)p;
  __half2 h0 = *(__half2*)&r.x;
  __half2 h1 = *(__half2*)&r.y;
  __half2 h2 = *(__half2*)&r.z;
  __half2 h3 = *(__half2*)&r.w;
  float2 f0 = __half22float2(h0);
  float2 f1 = __half22float2(h1);
  float2 f2 = __half22float2(h2);
  float2 f3 = __half22float2(h3);
  o[0] = f0.x; o[1] = f0.y; o[2] = f1.x; o[3] = f1.y;
  o[4] = f2.x; o[5] = f2.y; o[6] = f3.x; o[7] = f3.y;
}

// ---------------------------------------------------------------------------
// bf16 MFMA GEMM: C[M,N](+)=A[M,K]_bf16 @ Bt[N,K]_bf16^T. 128x128 tile.
// ACC: 0=store, 1=+=, 2=atomicAdd(float). BROW: 0 none, 1 bias[n-col],
// 2 bias[m-row]. TSTORE=1: store C^T fp16 (OT=__half). ACT=1: softplus.
// SPLITK: nonzero = per-z K-chunk size in elements (K arg = chunk size).
// ---------------------------------------------------------------------------
template <int ACC, int BROW, int TSTORE, int ACT, int SPLITK, typename OT>
__global__ __launch_bounds__(256) void gemm_bt_mfma(
    const u16* __restrict__ A, const u16* __restrict__ Bt,
    const float* __restrict__ bias, OT* __restrict__ C, int K, int lda,
    int ldb, int ldc) {
  if (SPLITK) {
    A += (size_t)blockIdx.z * SPLITK;
    Bt += (size_t)blockIdx.z * SPLITK;
  }
  __shared__ __align__(16) u16 As[128 * 32];
  __shared__ __align__(16) u16 Bs[128 * 32];
  const int tid = threadIdx.x;
  const int lane = tid & 63;
  const int wv = tid >> 6;
  const int n0 = blockIdx.x * 128;
  const int m0 = blockIdx.y * 128;
  const int wm0 = (wv & 1) * 64;
  const int wn0 = (wv >> 1) * 64;
  const int quad = lane >> 4;
  const int l16 = lane & 15;

  const int srow = wv * 32 + (lane >> 2);
  const int scol = (lane & 3) * 8;
  const u16* ga0 = A + (size_t)(m0 + srow) * lda + scol;
  const u16* ga1 = ga0 + (size_t)16 * lda;
  const u16* gb0 = Bt + (size_t)(n0 + srow) * ldb + scol;
  const u16* gb1 = gb0 + (size_t)16 * ldb;
  u16* la0 = &As[(wv * 32) * 32];
  u16* la1 = &As[(wv * 32 + 16) * 32];
  u16* lb0 = &Bs[(wv * 32) * 32];
  u16* lb1 = &Bs[(wv * 32 + 16) * 32];

  f32x4 acc[4][4] = {};

  for (int k0 = 0; k0 < K; k0 += 32) {
    __syncthreads();
    __builtin_amdgcn_global_load_lds((gvoid_t*)ga0, (lvoid_t*)la0, 16, 0, 0);
    __builtin_amdgcn_global_load_lds((gvoid_t*)ga1, (lvoid_t*)la1, 16, 0, 0);
    __builtin_amdgcn_global_load_lds((gvoid_t*)gb0, (lvoid_t*)lb0, 16, 0, 0);
    __builtin_amdgcn_global_load_lds((gvoid_t*)gb1, (lvoid_t*)lb1, 16, 0, 0);
    __syncthreads();
    bf16x8 af[4], bfr[4];
#pragma unroll
    for (int i = 0; i < 4; i++)
      af[i] = *(const bf16x8*)&As[(wm0 + i * 16 + l16) * 32 + quad * 8];
#pragma unroll
    for (int j = 0; j < 4; j++)
      bfr[j] = *(const bf16x8*)&Bs[(wn0 + j * 16 + l16) * 32 + quad * 8];
#pragma unroll
    for (int i = 0; i < 4; i++)
#pragma unroll
      for (int j = 0; j < 4; j++)
        acc[i][j] = __builtin_amdgcn_mfma_f32_16x16x32_bf16(af[i], bfr[j],
                                                            acc[i][j], 0, 0, 0);
    ga0 += 32; ga1 += 32; gb0 += 32; gb1 += 32;
  }

#pragma unroll
  for (int i = 0; i < 4; i++) {
#pragma unroll
    for (int j = 0; j < 4; j++) {
      const int col = n0 + wn0 + j * 16 + l16;
      const int rowb = m0 + wm0 + i * 16 + quad * 4;
      if (TSTORE) {
        __half* Ch = (__half*)C;
        union { __half2 h[2]; uint2 u; } pk;
        pk.h[0].x = __float2half(acc[i][j][0]);
        pk.h[0].y = __float2half(acc[i][j][1]);
        pk.h[1].x = __float2half(acc[i][j][2]);
        pk.h[1].y = __float2half(acc[i][j][3]);
        *(uint2*)(Ch + (size_t)col * ldc + rowb) = pk.u;
      } else {
        float bv = 0.f;
        if (BROW == 1) bv = bias[col];
#pragma unroll
        for (int r = 0; r < 4; r++) {
          float v = acc[i][j][r] + bv;
          if (BROW == 2) v += bias[rowb + r];
          if (ACT == 1) v = (v > 20.f) ? v : log1pf(expf(v));  // softplus
          OT* p = C + (size_t)(rowb + r) * ldc + col;
          if (ACC == 2) {
            atomicAdd((float*)p, v);
          } else {
            if (ACC == 1) v += (float)*p;
            *p = (OT)v;
          }
        }
      }
    }
  }
}

// ---------------------------------------------------------------------------
// fp32 [K,N] -> bf16 [N,K] transpose+convert (32x32 tiles)
// ---------------------------------------------------------------------------
__device__ __forceinline__ void transpose_cvt_body(
    const float* __restrict__ src, u16* __restrict__ dst, int K, int N,
    int bx, int by, int tid) {
  __shared__ float t[32][33];
  const int n0 = bx * 32;
  const int k0 = by * 32;
  const int c = tid & 31;
  const int r = tid >> 5;
#pragma unroll
  for (int rr = 0; rr < 4; rr++)
    t[r + rr * 8][c] = src[(size_t)(k0 + r + rr * 8) * N + n0 + c];
  __syncthreads();
#pragma unroll
  for (int rr = 0; rr < 4; rr++)
    dst[(size_t)(n0 + r + rr * 8) * K + k0 + c] = f2bf(t[c][r + rr * 8]);
}

__global__ __launch_bounds__(256) void transpose_cvt_kernel(
    const float* __restrict__ src, u16* __restrict__ dst, int K, int N) {
  transpose_cvt_body(src, dst, K, N, blockIdx.x, blockIdx.y, threadIdx.x);
}

// All per-layer weight transposes in ONE launch.
// blocks: [0,4096) winT, [4096,6144) woutT, [6144,6336) w_x16, [6336,6464) w_dt16
__global__ __launch_bounds__(256) void prep_weights_kernel(
    const float* __restrict__ w_in_l, const float* __restrict__ w_out_l,
    const float* __restrict__ w_x_l, const float* __restrict__ w_dt_l,
    u16* __restrict__ winT, u16* __restrict__ woutT, u16* __restrict__ w_x16,
    u16* __restrict__ w_dt16) {
  int bid = blockIdx.x;
  if (bid < 4096) {
    transpose_cvt_body(w_in_l, winT, DM, 2 * DI, bid & 127, bid >> 7,
                       threadIdx.x);
  } else if (bid < 6144) {
    bid -= 4096;
    transpose_cvt_body(w_out_l, woutT, DI, DM, bid & 31, bid >> 5,
                       threadIdx.x);
  } else if (bid < 6336) {
    bid -= 6144;
    transpose_cvt_body(w_x_l, w_x16, DI, 96, bid % 3, bid / 3, threadIdx.x);
  } else {
    bid -= 6336;
    transpose_cvt_body(w_dt_l, w_dt16, DR, DI, bid & 63, bid >> 6,
                       threadIdx.x);
  }
}

// u16 [K,N] -> u16 [N,K]  (yT -> y row-major)
__global__ __launch_bounds__(256) void transpose_u16_kernel(
    const u16* __restrict__ src, u16* __restrict__ dst, int K, int N) {
  __shared__ u16 t[32][33];
  const int n0 = blockIdx.x * 32;
  const int k0 = blockIdx.y * 32;
  const int c = threadIdx.x & 31;
  const int r = threadIdx.x >> 5;
#pragma unroll
  for (int rr = 0; rr < 4; rr++)
    t[r + rr * 8][c] = src[(size_t)(k0 + r + rr * 8) * N + n0 + c];
  __syncthreads();
#pragma unroll
  for (int rr = 0; rr < 4; rr++)
    dst[(size_t)(n0 + r + rr * 8) * K + k0 + c] = t[c][r + rr * 8];
}

// flat fp32 -> bf16
__global__ __launch_bounds__(256) void cvt_kernel(const float* __restrict__ src,
                                                  u16* __restrict__ dst) {
  const int i = blockIdx.x * 256 + threadIdx.x;
  const float4 v = ((const float4*)src)[i];
  ushort4 o;
  o.x = f2bf(v.x);
  o.y = f2bf(v.y);
  o.z = f2bf(v.z);
  o.w = f2bf(v.w);
  ((ushort4*)dst)[i] = o;
}

// ---------------------------------------------------------------------------
// RMSNorm -> bf16
// ---------------------------------------------------------------------------
__global__ __launch_bounds__(256) void rmsnorm_kernel(
    const float* __restrict__ h, const float* __restrict__ w,
    u16* __restrict__ out) {
  const int row = blockIdx.x;
  const int tid = threadIdx.x;
  const float4 v = *(const float4*)(h + (size_t)row * DM + tid * 4);
  float ss = v.x * v.x + v.y * v.y + v.z * v.z + v.w * v.w;
#pragma unroll
  for (int off = 32; off > 0; off >>= 1) ss += __shfl_xor(ss, off);
  __shared__ float red[4];
  if ((tid & 63) == 0) red[tid >> 6] = ss;
  __syncthreads();
  float tot = red[0] + red[1] + red[2] + red[3];
  const float inv = rsqrtf(tot / (float)DM + EPS);
  const float4 wv = *(const float4*)(w + tid * 4);
  ushort4 o;
  o.x = f2bf(v.x * inv * wv.x);
  o.y = f2bf(v.y * inv * wv.y);
  o.z = f2bf(v.z * inv * wv.z);
  o.w = f2bf(v.w * inv * wv.w);
  *(ushort4*)(out + (size_t)row * DM + tid * 4) = o;
}

// ---------------------------------------------------------------------------
// Causal conv + bias + silu, 32x32 tile. Outputs BOTH:
//   uT fp16 [d][row] (for scan)  and  u16rm bf16 [row][d] (for w_x MFMA).
// ---------------------------------------------------------------------------
__global__ __launch_bounds__(256) void conv_silu_tile_kernel(
    const __half* __restrict__ xpT, const float* __restrict__ wc,
    const float* __restrict__ bc, __half* __restrict__ uT,
    u16* __restrict__ u16rm) {
  __shared__ u16 tile[32][33];  // [r-local][d-local] bf16
  const int tid = threadIdx.x;
  const int d0 = blockIdx.x * 32;
  const int r0 = blockIdx.y * 32;  // 32 | 224 => tile within one batch
  const int dl = tid >> 3;
  const int rq = (tid & 7) * 4;
  const int d = d0 + dl;
  const int r = r0 + rq;
  const int t = r % L_;
  const __half* row = xpT + (size_t)d * ROWS + r;
  float v[4];
  load4h(row, v);
  float p0 = 0.f, p1 = 0.f, p2 = 0.f;
  if (t > 0) {
    p0 = __half2float(row[-3]);
    p1 = __half2float(row[-2]);
    p2 = __half2float(row[-1]);
  }
  const float w0 = wc[d * 4 + 0], w1 = wc[d * 4 + 1], w2 = wc[d * 4 + 2],
              w3 = wc[d * 4 + 3];
  const float bb = bc[d];
  float o[4];
  float s;
  s = bb + p0 * w0 + p1 * w1 + p2 * w2 + v[0] * w3; o[0] = s / (1.f + expf(-s));
  s = bb + p1 * w0 + p2 * w1 + v[0] * w2 + v[1] * w3; o[1] = s / (1.f + expf(-s));
  s = bb + p2 * w0 + v[0] * w1 + v[1] * w2 + v[2] * w3; o[2] = s / (1.f + expf(-s));
  s = bb + v[0] * w0 + v[1] * w1 + v[2] * w2 + v[3] * w3; o[3] = s / (1.f + expf(-s));
  union { __half2 h[2]; uint2 u; } pk;
  pk.h[0].x = __float2half(o[0]); pk.h[0].y = __float2half(o[1]);
  pk.h[1].x = __float2half(o[2]); pk.h[1].y = __float2half(o[3]);
  *(uint2*)(uT + (size_t)d * ROWS + r) = pk.u;
#pragma unroll
  for (int i = 0; i < 4; i++) tile[rq + i][dl] = f2bf(o[i]);
  __syncthreads();
  const int rl = tid >> 3;
  const int dq = (tid & 7) * 4;
  ushort4 ov;
  ov.x = tile[rl][dq + 0];
  ov.y = tile[rl][dq + 1];
  ov.z = tile[rl][dq + 2];
  ov.w = tile[rl][dq + 3];
  *(ushort4*)(u16rm + (size_t)(r0 + rl) * DI + d0 + dq) = ov;
}

// ---------------------------------------------------------------------------
// Selective scan v8: v7 structure + B/C hoisted to registers per 8-group.
// 512 blocks x 4 waves; wave = 8 ch, lane=(c<<3)|sg, states {2sg,2sg+1}.
// ---------------------------------------------------------------------------
__global__ __launch_bounds__(256) void scan_kernel(
    const __half* __restrict__ dtT, const __half* __restrict__ uT,
    const __half* __restrict__ zT, const float* __restrict__ xdblT,
    const float* __restrict__ A_log, const float* __restrict__ Dp,
    u16* __restrict__ yT) {
  __shared__ __align__(16) __half dtu[4][2][512];
  __shared__ __align__(16) __half zbuf[4][2][512];
  __shared__ __align__(16) float bcb[2][32 * 36];

  const int tid = threadIdx.x;
  const int wv = tid >> 6;
  const int lane = tid & 63;
  const int b = blockIdx.x >> 6;
  const int d0 = ((blockIdx.x & 63) << 5) + wv * 8;
  const int c = lane >> 3;
  const int sg = lane & 7;
  const int d = d0 + c;
  const int s0 = sg * 2;

  const int sl = lane & 31;
  const size_t srcoff =
      (size_t)(d0 + (sl & 7)) * ROWS + (size_t)b * L_ + (sl >> 3) * 8;
  const __half* gdtu = (lane < 32 ? dtT : uT) + srcoff;
  const __half* gz = zT + srcoff;

  const int bs = tid >> 3;
  const int bt4 = (tid & 7) * 4;
  const float* gbc = xdblT + (size_t)(DR + bs) * ROWS + (size_t)b * L_ + bt4;

  const float2 Al = *(const float2*)(A_log + (size_t)d * DS + s0);
  const float A20 = -expf(Al.x) * 1.44269504f;
  const float A21 = -expf(Al.y) * 1.44269504f;
  const float Dpd = Dp[d];
  u16* yp = yT + (size_t)d * ROWS + b * L_;

  float hs0 = 0.f, hs1 = 0.f;

  auto stage_dtuz = [&](int t0, int p) {
    __builtin_amdgcn_global_load_lds((gvoid_t*)(gdtu + t0),
                                     (lvoid_t*)&dtu[wv][p][0], 16, 0, 0);
    __builtin_amdgcn_global_load_lds((gvoid_t*)(gz + t0),
                                     (lvoid_t*)&zbuf[wv][p][0], 16, 0, 0);
  };

  {
    float4 bc0 = *(const float4*)gbc;
    stage_dtuz(0, 0);
    __builtin_amdgcn_s_waitcnt(0x0f70);  // vmcnt(0)
    *(float4*)&bcb[0][bs * 36 + bt4] = bc0;
    __syncthreads();
  }

  for (int ch = 0; ch < L_ / 32; ch++) {
    const int p = ch & 1;
    const int t0 = ch * 32;
    float4 bcn;
    const bool more = (ch + 1 < L_ / 32);
    if (more) {
      bcn = *(const float4*)(gbc + t0 + 32);
      stage_dtuz(t0 + 32, p ^ 1);
    }
#pragma unroll
    for (int g = 0; g < 4; g++) {  // 4 groups of 8 steps
      float dt8[8], u8[8], z8[8];
      load8h(&dtu[wv][p][g * 64 + c * 8], dt8);
      load8h(&dtu[wv][p][256 + g * 64 + c * 8], u8);
      load8h(&zbuf[wv][p][g * 64 + c * 8], z8);
      float Bv0[8], Bv1[8], Cv0[8], Cv1[8];
      *(float4*)&Bv0[0] = *(const float4*)&bcb[p][s0 * 36 + g * 8];
      *(float4*)&Bv0[4] = *(const float4*)&bcb[p][s0 * 36 + g * 8 + 4];
      *(float4*)&Bv1[0] = *(const float4*)&bcb[p][(s0 + 1) * 36 + g * 8];
      *(float4*)&Bv1[4] = *(const float4*)&bcb[p][(s0 + 1) * 36 + g * 8 + 4];
      *(float4*)&Cv0[0] = *(const float4*)&bcb[p][(16 + s0) * 36 + g * 8];
      *(float4*)&Cv0[4] = *(const float4*)&bcb[p][(16 + s0) * 36 + g * 8 + 4];
      *(float4*)&Cv1[0] = *(const float4*)&bcb[p][(17 + s0) * 36 + g * 8];
      *(float4*)&Cv1[4] = *(const float4*)&bcb[p][(17 + s0) * 36 + g * 8 + 4];
      union { u16 h[8]; uint4 v; } yb;
#pragma unroll
      for (int k = 0; k < 8; k++) {
        const float dtv = dt8[k];
        const float uu = u8[k];
        const float du = dtv * uu;
        hs0 = fmaf(hs0, exp2f(dtv * A20), du * Bv0[k]);
        hs1 = fmaf(hs1, exp2f(dtv * A21), du * Bv1[k]);
        float pr = fmaf(hs1, Cv1[k], hs0 * Cv0[k]);
        pr += __shfl_xor(pr, 1);
        pr += __shfl_xor(pr, 2);
        pr += __shfl_xor(pr, 4);
        if (sg == 0) {
          const float zz = z8[k];
          float yv = pr + Dpd * uu;
          yv *= zz / (1.f + expf(-zz));
          yb.h[k] = f2bf(yv);
        }
      }
      if (sg == 0) *(uint4*)(yp + t0 + g * 8) = yb.v;
    }
    if (more) {
      __builtin_amdgcn_s_waitcnt(0x0f70);
      *(float4*)&bcb[p ^ 1][bs * 36 + bt4] = bcn;
    }
    __syncthreads();
  }
}

// ---------------------------------------------------------------------------
// Final: rmsnorm(h[b, L-1, :]) @ w_fc + b_fc
// ---------------------------------------------------------------------------
__global__ __launch_bounds__(256) void final_kernel(
    const float* __restrict__ h, const float* __restrict__ fnw,
    const float* __restrict__ w_fc, const float* __restrict__ b_fc,
    float* __restrict__ out) {
  const int b = blockIdx.x;
  const int tid = threadIdx.x;
  const size_t row = ((size_t)b * L_ + (L_ - 1)) * DM;
  const float4 v = *(const float4*)(h + row + tid * 4);
  float ss = v.x * v.x + v.y * v.y + v.z * v.z + v.w * v.w;
#pragma unroll
  for (int off = 32; off > 0; off >>= 1) ss += __shfl_xor(ss, off);
  __shared__ float red[4];
  if ((tid & 63) == 0) red[tid >> 6] = ss;
  __syncthreads();
  float tot = red[0] + red[1] + red[2] + red[3];
  const float inv = rsqrtf(tot / (float)DM + EPS);
  const float4 wv = *(const float4*)(fnw + tid * 4);
  float hn[4] = {v.x * inv * wv.x, v.y * inv * wv.y, v.z * inv * wv.z,
                 v.w * inv * wv.w};
  float partial[NC];
#pragma unroll
  for (int j = 0; j < NC; j++) partial[j] = 0.f;
#pragma unroll
  for (int e = 0; e < 4; e++) {
    const int dd = tid * 4 + e;
#pragma unroll
    for (int j = 0; j < NC; j++)
      partial[j] = fmaf(hn[e], w_fc[dd * NC + j], partial[j]);
  }
  __shared__ float red2[256][NC];
  for (int j = 0; j < NC; j++) red2[tid][j] = partial[j];
  __syncthreads();
  for (int stride = 128; stride > 0; stride >>= 1) {
    if (tid < stride)
      for (int j = 0; j < NC; j++) red2[tid][j] += red2[tid + stride][j];
    __syncthreads();
  }
  if (tid < NC) out[b * NC + tid] = red2[0][tid] + b_fc[tid];
}

// ---------------------------------------------------------------------------
extern "C" void kernel_launch(void* const* d_in, const int* in_sizes, int n_in,
                              void* d_out, int out_size, void* d_ws,
                              size_t ws_size, hipStream_t stream) {
  const float* x = (const float*)d_in[0];
  const float* w_proj = (const float*)d_in[1];
  const float* b_proj = (const float*)d_in[2];
  const float* norm_w = (const float*)d_in[3];
  const float* w_in = (const float*)d_in[4];
  const float* w_conv = (const float*)d_in[5];
  const float* b_conv = (const float*)d_in[6];
  const float* w_x = (const float*)d_in[7];
  const float* w_dt = (const float*)d_in[8];
  const float* b_dt = (const float*)d_in[9];
  const float* A_log = (const float*)d_in[10];
  const float* Dp = (const float*)d_in[11];
  const float* w_out = (const float*)d_in[12];
  const float* fnw = (const float*)d_in[13];
  const float* w_fc = (const float*)d_in[14];
  const float* b_fc = (const float*)d_in[15];
  float* out = (float*)d_out;

  // Workspace layout (float units)
  float* ws = (float*)d_ws;
  float* h = ws;                               // 1,835,008
  float* p1 = h + 1835008;
  __half* xzT = (__half*)p1;                   // [4096][1792] fp16 (3,670,016 f)
  float* p2 = p1 + 3670016;
  __half* uT = (__half*)p2;                    // [2048][1792] fp16 (1,835,008 f)
  float* p3 = p2 + 1835008;
  float* xdblT = p3;                           // [128][1792] fp32 (229,376 f)
  float* p4 = p3 + 229376;
  __half* dtT = (__half*)p4;                   // [2048][1792] fp16 (1,835,008 f)
  float* p5 = p4 + 1835008;
  u16* yT = (u16*)p5;                          // [2048][1792] bf16 (1,835,008 f)
  float* p6 = p5 + 1835008;
  u16* y16 = (u16*)p6;                         // [1792][2048] bf16 (1,835,008 f)
  u16* xn16 = y16;                             // alias (disjoint liveness)
  float* p7 = p6 + 1835008;
  u16* u16rm = (u16*)p7;                       // [1792][2048] bf16 (1,835,008 f)
  float* p8 = p7 + 1835008;
  u16* x16 = (u16*)p8;                         // 602,112 f
  float* p9 = p8 + 602112;
  u16* wprojT = (u16*)p9;                      // 344,064 f
  float* p10 = p9 + 344064;
  u16* winT = (u16*)p10;                       // 2,097,152 f
  float* p11 = p10 + 2097152;
  u16* woutT = (u16*)p11;                      // 1,048,576 f
  float* p12 = p11 + 1048576;
  u16* w_x16 = (u16*)p12;                      // [128][2048] bf16 (131,072 f)
  float* p13 = p12 + 131072;
  u16* w_dt16 = (u16*)p13;                     // [2048][64] bf16 (65,536 f)
  float* p14 = p13 + 65536;
  u16* dtr16 = (u16*)p14;                      // [1792][64] bf16 (57,344 f)

  const dim3 blk(256);

  cvt_kernel<<<ROWS * DLOC / 1024, blk, 0, stream>>>(x, x16);
  transpose_cvt_kernel<<<dim3(DM / 32, DLOC / 32), blk, 0, stream>>>(
      w_proj, wprojT, DLOC, DM);

  // h = x @ w_proj + b_proj
  gemm_bt_mfma<0, 1, 0, 0, 0, float>
      <<<dim3(DM / 128, ROWS / 128), blk, 0, stream>>>(
          x16, wprojT, b_proj, h, DLOC, DLOC, DLOC, DM);

  for (int l = 0; l < NL; l++) {
    // all weight transposes in one launch
    prep_weights_kernel<<<6464, blk, 0, stream>>>(
        w_in + (size_t)l * DM * 2 * DI, w_out + (size_t)l * DI * DM,
        w_x + (size_t)l * DI * 96, w_dt + (size_t)l * DR * DI, winT, woutT,
        w_x16, w_dt16);

    // xn = rmsnorm(h) -> bf16
    rmsnorm_kernel<<<ROWS, blk, 0, stream>>>(h, norm_w + (size_t)l * DM, xn16);
    // xzT[4096][1792] = (xn @ w_in[l])^T  (fp16 T-store)
    gemm_bt_mfma<0, 0, 1, 0, 0, __half>
        <<<dim3(2 * DI / 128, ROWS / 128), blk, 0, stream>>>(
            xn16, winT, nullptr, (__half*)xzT, DM, DM, DM, ROWS);
    // uT fp16 + u16rm bf16 = silu(conv(xpT) + b_conv)
    conv_silu_tile_kernel<<<dim3(DI / 32, ROWS / 32), blk, 0, stream>>>(
        xzT, w_conv + (size_t)l * DI * DC, b_conv + (size_t)l * DI, uT, u16rm);
    // xdblT[128][1792] = w_x16 @ u  (MFMA split-K x4, atomicAdd)
    hipMemsetAsync(xdblT, 0, (size_t)128 * ROWS * sizeof(float), stream);
    gemm_bt_mfma<2, 0, 0, 0, 512, float>
        <<<dim3(ROWS / 128, 1, 4), blk, 0, stream>>>(
            w_x16, u16rm, nullptr, xdblT, 512, DI, DI, ROWS);
    // dtr16[1792][64] = cvt(xdblT rows 0..63 ^T)
    transpose_cvt_kernel<<<dim3(ROWS / 32, DR / 32), blk, 0, stream>>>(
        xdblT, dtr16, DR, ROWS);
    // dtT[2048][1792] = softplus(w_dt16 @ dtr^T + b_dt[m]) -> fp16
    gemm_bt_mfma<0, 2, 0, 1, 0, __half>
        <<<dim3(ROWS / 128, DI / 128), blk, 0, stream>>>(
            w_dt16, dtr16, b_dt + (size_t)l * DI, dtT, DR, DR, DR, ROWS);
    // yT = scan(...)
    scan_kernel<<<dim3(B_ * (DI / 32)), blk, 0, stream>>>(
        dtT, uT, xzT + (size_t)DI * ROWS, xdblT, A_log + (size_t)l * DI * DS,
        Dp + (size_t)l * DI, yT);
    // y16 = yT^T
    transpose_u16_kernel<<<dim3(ROWS / 32, DI / 32), blk, 0, stream>>>(
        yT, y16, DI, ROWS);
    // h += y @ w_out[l]
    gemm_bt_mfma<1, 0, 0, 0, 0, float>
        <<<dim3(DM / 128, ROWS / 128), blk, 0, stream>>>(
            y16, woutT, nullptr, h, DI, DI, DI, DM);
  }

  final_kernel<<<B_, blk, 0, stream>>>(h, fnw, w_fc, b_fc, out);
}